// Round 1
// baseline (883.989 us; speedup 1.0000x reference)
//
#include <hip/hip_runtime.h>

// CrossAttention: B=16, Sq=4096, Dm=512, Skv=77, Dc=768, H=8, Dh=64, inner=512
// Pipeline:
//   1. transpose_split: W* (fp32 [K][N]) -> W*_t hi/lo bf16 pairs [N][K]   (ws)
//   2. gemm_split<fp32A>: k = ctx@Wk, v = ctx@Wv  -> fp32 [1232][512]      (ws)
//   3. gemm_split<fp32A>: q = x@Wq -> fp32 [65536][512]                    (d_out as scratch)
//   4. attn_kernel: softmax(q k^T/8) v -> split bf16 pair [65536][512]     (ws)
//   5. gemm_split<pairA,+bias>: out = attn@Wout + bout -> fp32             (d_out)
// Precision: all GEMMs use 3-pass split-bf16 MFMA (hh + hl + lh) ~= fp32.
// ws required ~= 138 MiB.

typedef unsigned short u16;
typedef unsigned int u32;
typedef __attribute__((ext_vector_type(8))) short short8;
typedef __attribute__((ext_vector_type(4))) float f32x4;
typedef __attribute__((ext_vector_type(4))) u16 u16x4;

__device__ __forceinline__ u16 f2bf(float f) {
    union { float f; u32 u; } c; c.f = f;
    u32 r = (c.u + 0x7FFFu + ((c.u >> 16) & 1u)) >> 16;   // RNE
    return (u16)r;
}
__device__ __forceinline__ float bf2f(u16 u) {
    union { u32 u; float f; } c; c.u = ((u32)u) << 16;
    return c.f;
}

// ---------------- weight transpose + split ----------------
// W fp32 [K][N] -> Ht/Lt bf16 [N][K]
__global__ __launch_bounds__(256) void transpose_split(
    const float* __restrict__ W, u16* __restrict__ Ht, u16* __restrict__ Lt,
    int K, int N)
{
    int idx = blockIdx.x * 256 + threadIdx.x;
    if (idx >= N * K) return;
    int n = idx / K, k = idx - n * K;
    float f = W[(size_t)k * N + n];
    u16 h = f2bf(f);
    u16 l = f2bf(f - bf2f(h));
    Ht[idx] = h;
    Lt[idx] = l;
}

// ---------------- split-bf16 MFMA GEMM ----------------
// C[M,N] = A[M,K] @ B[K,N] (+ bias). B passed as transposed split pair [N][K].
// APAIR=false: A fp32, converted to hi/lo during staging.
// APAIR=true:  A passed as split bf16 pair (Aptr=hi, Alptr=lo) [M][K].
#define BM 128
#define BN 128
#define BKK 32
#define PK 40   // padded LDS K-stride (bf16 elems): breaks b128 bank conflicts

template<bool APAIR, bool BIAS>
__global__ __launch_bounds__(256) void gemm_split(
    const void* __restrict__ Aptr, const u16* __restrict__ Alptr,
    const u16* __restrict__ Bh, const u16* __restrict__ Bl,
    const float* __restrict__ bias, float* __restrict__ C,
    int M, int N, int K)
{
    __shared__ u16 lAh[BM * PK];
    __shared__ u16 lAl[BM * PK];
    __shared__ u16 lBh[BN * PK];
    __shared__ u16 lBl[BN * PK];

    const int t = threadIdx.x;
    const int lane = t & 63;
    const int wid = t >> 6;
    const int wr = wid >> 1, wc = wid & 1;       // 2x2 waves of 64x64
    const int m0 = blockIdx.x * BM, n0 = blockIdx.y * BN;
    const int ar = lane & 15;
    const int kc = (lane >> 4) << 3;             // k-offset within BK: 0,8,16,24

    f32x4 acc[4][4] = {};

    for (int k0 = 0; k0 < K; k0 += BKK) {
        // ---- stage A ----
        if constexpr (!APAIR) {
            const float* A = (const float*)Aptr;
            #pragma unroll
            for (int it = 0; it < 4; ++it) {
                int idx = t + it * 256;          // 1024 float4 chunks = 128x32
                int row = idx >> 3;
                int c4 = (idx & 7) << 2;
                int gr = m0 + row;
                float4 v = make_float4(0.f, 0.f, 0.f, 0.f);
                if (gr < M) v = *(const float4*)(A + (size_t)gr * K + k0 + c4);
                u16 h0 = f2bf(v.x), h1 = f2bf(v.y), h2 = f2bf(v.z), h3 = f2bf(v.w);
                u16 l0 = f2bf(v.x - bf2f(h0));
                u16 l1 = f2bf(v.y - bf2f(h1));
                u16 l2 = f2bf(v.z - bf2f(h2));
                u16 l3 = f2bf(v.w - bf2f(h3));
                *(u16x4*)(lAh + row * PK + c4) = (u16x4){h0, h1, h2, h3};
                *(u16x4*)(lAl + row * PK + c4) = (u16x4){l0, l1, l2, l3};
            }
        } else {
            const u16* Ah = (const u16*)Aptr;
            #pragma unroll
            for (int it = 0; it < 2; ++it) {
                int idx = t + it * 256;          // 512 short8 chunks = 128x32
                int row = idx >> 2;
                int c8 = (idx & 3) << 3;
                int gr = m0 + row;
                short8 vh = {0, 0, 0, 0, 0, 0, 0, 0};
                short8 vl = {0, 0, 0, 0, 0, 0, 0, 0};
                if (gr < M) {
                    vh = *(const short8*)(Ah + (size_t)gr * K + k0 + c8);
                    vl = *(const short8*)(Alptr + (size_t)gr * K + k0 + c8);
                }
                *(short8*)(lAh + row * PK + c8) = vh;
                *(short8*)(lAl + row * PK + c8) = vl;
            }
        }
        // ---- stage B (N always a multiple of BN here) ----
        #pragma unroll
        for (int it = 0; it < 2; ++it) {
            int idx = t + it * 256;
            int row = idx >> 2;
            int c8 = (idx & 3) << 3;
            *(short8*)(lBh + row * PK + c8) =
                *(const short8*)(Bh + (size_t)(n0 + row) * K + k0 + c8);
            *(short8*)(lBl + row * PK + c8) =
                *(const short8*)(Bl + (size_t)(n0 + row) * K + k0 + c8);
        }
        __syncthreads();

        // ---- fragments + MFMA ----
        short8 fah[4], fal[4], fbh[4], fbl[4];
        #pragma unroll
        for (int m = 0; m < 4; ++m) {
            fah[m] = *(const short8*)(lAh + (wr * 64 + m * 16 + ar) * PK + kc);
            fal[m] = *(const short8*)(lAl + (wr * 64 + m * 16 + ar) * PK + kc);
        }
        #pragma unroll
        for (int n = 0; n < 4; ++n) {
            fbh[n] = *(const short8*)(lBh + (wc * 64 + n * 16 + ar) * PK + kc);
            fbl[n] = *(const short8*)(lBl + (wc * 64 + n * 16 + ar) * PK + kc);
        }
        #pragma unroll
        for (int m = 0; m < 4; ++m) {
            #pragma unroll
            for (int n = 0; n < 4; ++n) {
                acc[m][n] = __builtin_amdgcn_mfma_f32_16x16x32_bf16(fah[m], fbh[n], acc[m][n], 0, 0, 0);
                acc[m][n] = __builtin_amdgcn_mfma_f32_16x16x32_bf16(fah[m], fbl[n], acc[m][n], 0, 0, 0);
                acc[m][n] = __builtin_amdgcn_mfma_f32_16x16x32_bf16(fal[m], fbh[n], acc[m][n], 0, 0, 0);
            }
        }
        __syncthreads();
    }

    // ---- epilogue: C/D layout col=lane&15, row=(lane>>4)*4+r ----
    #pragma unroll
    for (int n = 0; n < 4; ++n) {
        int col = n0 + wc * 64 + n * 16 + (lane & 15);
        float bv = 0.f;
        if constexpr (BIAS) bv = bias[col];
        #pragma unroll
        for (int m = 0; m < 4; ++m) {
            #pragma unroll
            for (int r = 0; r < 4; ++r) {
                int row = m0 + wr * 64 + m * 16 + ((lane >> 4) << 2) + r;
                if (row < M) C[(size_t)row * N + col] = acc[m][n][r] + bv;
            }
        }
    }
}

// ---------------- attention (fp32), outputs split bf16 pair ----------------
// grid: (Sq/32, H, B), block 256
__global__ __launch_bounds__(256) void attn_kernel(
    const float* __restrict__ q, const float* __restrict__ kbuf, const float* __restrict__ vbuf,
    u16* __restrict__ outH, u16* __restrict__ outL)
{
    __shared__ float sK[77 * 64];
    __shared__ float sV[77 * 64];
    __shared__ float sQ[32 * 68];   // padded stride 68
    __shared__ float sS[32 * 80];   // padded stride 80

    const int t = threadIdx.x;
    const int q0 = blockIdx.x << 5;
    const int head = blockIdx.y;
    const int b = blockIdx.z;

    const size_t kvbase = ((size_t)b * 77) * 512 + head * 64;
    for (int i = t; i < 77 * 16; i += 256) {
        int r = i >> 4, c4 = (i & 15) << 2;
        *(float4*)(sK + r * 64 + c4) = *(const float4*)(kbuf + kvbase + (size_t)r * 512 + c4);
        *(float4*)(sV + r * 64 + c4) = *(const float4*)(vbuf + kvbase + (size_t)r * 512 + c4);
    }
    const size_t qbase = ((size_t)(b * 4096 + q0)) * 512 + head * 64;
    for (int i = t; i < 32 * 16; i += 256) {
        int r = i >> 4, c4 = (i & 15) << 2;
        *(float4*)(sQ + r * 68 + c4) = *(const float4*)(q + qbase + (size_t)r * 512 + c4);
    }
    __syncthreads();

    // scores: thread (qi = t&31, sj = t>>5); q row held in registers
    {
        const int qi = t & 31, sj = t >> 5;
        float4 qr[16];
        #pragma unroll
        for (int u = 0; u < 16; ++u) qr[u] = *(float4*)(sQ + qi * 68 + (u << 2));
        for (int sb = 0; sb < 10; ++sb) {
            int si = (sb << 3) + sj;
            if (si < 77) {
                float a = 0.f;
                #pragma unroll
                for (int u = 0; u < 16; ++u) {
                    float4 kv = *(float4*)(sK + si * 64 + (u << 2));
                    a += qr[u].x * kv.x + qr[u].y * kv.y + qr[u].z * kv.z + qr[u].w * kv.w;
                }
                sS[qi * 80 + si] = a * 0.125f;   // * D_HEAD^-0.5
            }
        }
    }
    __syncthreads();

    // softmax: 8 threads per row, shuffle reduce within 8-lane group
    {
        const int row = t >> 3, tj = t & 7;
        float m = -1e30f;
        for (int i = tj; i < 77; i += 8) m = fmaxf(m, sS[row * 80 + i]);
        m = fmaxf(m, __shfl_xor(m, 1));
        m = fmaxf(m, __shfl_xor(m, 2));
        m = fmaxf(m, __shfl_xor(m, 4));
        float s = 0.f;
        for (int i = tj; i < 77; i += 8) {
            float e = __expf(sS[row * 80 + i] - m);
            sS[row * 80 + i] = e;
            s += e;
        }
        s += __shfl_xor(s, 1); s += __shfl_xor(s, 2); s += __shfl_xor(s, 4);
        float inv = 1.f / s;
        for (int i = tj; i < 77; i += 8) sS[row * 80 + i] *= inv;
    }
    __syncthreads();

    // PV: thread (qi = t>>3, dj = t&7) -> 8 outputs d = dj*8..dj*8+7
    {
        const int qi = t >> 3, dj = t & 7;
        float a[8] = {0.f, 0.f, 0.f, 0.f, 0.f, 0.f, 0.f, 0.f};
        for (int si = 0; si < 77; ++si) {
            float p = sS[qi * 80 + si];
            float4 v0 = *(float4*)(sV + si * 64 + (dj << 3));
            float4 v1 = *(float4*)(sV + si * 64 + (dj << 3) + 4);
            a[0] += p * v0.x; a[1] += p * v0.y; a[2] += p * v0.z; a[3] += p * v0.w;
            a[4] += p * v1.x; a[5] += p * v1.y; a[6] += p * v1.z; a[7] += p * v1.w;
        }
        size_t base = ((size_t)(b * 4096 + q0 + qi)) * 512 + head * 64 + (dj << 3);
        short8 hv, lv;
        #pragma unroll
        for (int u = 0; u < 8; ++u) {
            u16 hh = f2bf(a[u]);
            hv[u] = (short)hh;
            lv[u] = (short)f2bf(a[u] - bf2f(hh));
        }
        *(short8*)(outH + base) = hv;
        *(short8*)(outL + base) = lv;
    }
}

extern "C" void kernel_launch(void* const* d_in, const int* in_sizes, int n_in,
                              void* d_out, int out_size, void* d_ws, size_t ws_size,
                              hipStream_t stream)
{
    const float* x    = (const float*)d_in[0];   // [16,4096,512]
    const float* ctx  = (const float*)d_in[1];   // [16,77,768]
    const float* Wq   = (const float*)d_in[2];   // [512,512]
    const float* Wk   = (const float*)d_in[3];   // [768,512]
    const float* Wv   = (const float*)d_in[4];   // [768,512]
    const float* Wout = (const float*)d_in[5];   // [512,512]
    const float* bout = (const float*)d_in[6];   // [512]

    char* ws = (char*)d_ws;
    size_t off = 0;
    auto alloc = [&](size_t bytes) -> void* {
        void* p = ws + off;
        off += (bytes + 255) & ~(size_t)255;
        return p;
    };
    u16* WqH = (u16*)alloc(512 * 512 * 2);
    u16* WqL = (u16*)alloc(512 * 512 * 2);
    u16* WkH = (u16*)alloc(768 * 512 * 2);
    u16* WkL = (u16*)alloc(768 * 512 * 2);
    u16* WvH = (u16*)alloc(768 * 512 * 2);
    u16* WvL = (u16*)alloc(768 * 512 * 2);
    u16* WoH = (u16*)alloc(512 * 512 * 2);
    u16* WoL = (u16*)alloc(512 * 512 * 2);
    float* kf = (float*)alloc((size_t)1232 * 512 * 4);
    float* vf = (float*)alloc((size_t)1232 * 512 * 4);
    u16* attnH = (u16*)alloc((size_t)16 * 4096 * 512 * 2);
    u16* attnL = (u16*)alloc((size_t)16 * 4096 * 512 * 2);
    (void)ws_size; (void)in_sizes; (void)n_in; (void)out_size;

    float* q = (float*)d_out;   // q scratch lives in d_out, overwritten by final GEMM

    // 1. weight splits (transposed)
    transpose_split<<<dim3(1024), dim3(256), 0, stream>>>(Wq, WqH, WqL, 512, 512);
    transpose_split<<<dim3(1536), dim3(256), 0, stream>>>(Wk, WkH, WkL, 768, 512);
    transpose_split<<<dim3(1536), dim3(256), 0, stream>>>(Wv, WvH, WvL, 768, 512);
    transpose_split<<<dim3(1024), dim3(256), 0, stream>>>(Wout, WoH, WoL, 512, 512);

    // 2. k/v projections: [1232,768] @ [768,512]
    gemm_split<false, false><<<dim3(10, 4), dim3(256), 0, stream>>>(
        (const void*)ctx, (const u16*)nullptr, WkH, WkL, (const float*)nullptr, kf, 1232, 512, 768);
    gemm_split<false, false><<<dim3(10, 4), dim3(256), 0, stream>>>(
        (const void*)ctx, (const u16*)nullptr, WvH, WvL, (const float*)nullptr, vf, 1232, 512, 768);

    // 3. q projection: [65536,512] @ [512,512] -> d_out
    gemm_split<false, false><<<dim3(512, 4), dim3(256), 0, stream>>>(
        (const void*)x, (const u16*)nullptr, WqH, WqL, (const float*)nullptr, q, 65536, 512, 512);

    // 4. attention -> split bf16 pair
    attn_kernel<<<dim3(128, 8, 16), dim3(256), 0, stream>>>(q, kf, vf, attnH, attnL);

    // 5. output projection + bias -> d_out
    gemm_split<true, true><<<dim3(512, 4), dim3(256), 0, stream>>>(
        (const void*)attnH, attnL, WoH, WoL, bout, (float*)d_out, 65536, 512, 512);
}

// Round 2
// 623.894 us; speedup vs baseline: 1.4169x; 1.4169x over previous
//
#include <hip/hip_runtime.h>

// CrossAttention: B=16, Sq=4096, Dm=512, Skv=77, Dc=768, H=8, Dh=64, inner=512
// Pipeline (all GEMMs 3-pass split-bf16 MFMA ~= fp32):
//   1. transpose_split: W* fp32 [K][N] -> hi/lo bf16 [N][K]                 (ws)
//   2. gemm OUT_PAIR : k = ctx@Wk -> split pair [1240pad][512]              (ws)
//      gemm OUT_PAIRT: v = ctx@Wv -> Vt split pair [16][512][96pad]         (ws)
//   3. gemm OUT_PAIR : q = x@Wq -> split pair [65536][512]                  (d_out)
//   4. attn_mfma: MFMA scores + in-reg softmax + MFMA PV -> split pair      (ws)
//   5. gemm OUT_F32+bias: out = attn@Wout + bout -> fp32                    (d_out)

typedef unsigned short u16;
typedef unsigned int u32;
typedef __attribute__((ext_vector_type(8))) short short8;
typedef __attribute__((ext_vector_type(4))) float f32x4;
typedef __attribute__((ext_vector_type(4))) u16 u16x4;

__device__ __forceinline__ u16 f2bf(float f) {
    union { float f; u32 u; } c; c.f = f;
    u32 r = (c.u + 0x7FFFu + ((c.u >> 16) & 1u)) >> 16;   // RNE
    return (u16)r;
}
__device__ __forceinline__ float bf2f(u16 u) {
    union { u32 u; float f; } c; c.u = ((u32)u) << 16;
    return c.f;
}
__device__ __forceinline__ f32x4 mfma16(short8 a, short8 b, f32x4 c) {
    return __builtin_amdgcn_mfma_f32_16x16x32_bf16(a, b, c, 0, 0, 0);
}

// ---------------- weight transpose + split ----------------
__global__ __launch_bounds__(256) void transpose_split(
    const float* __restrict__ W, u16* __restrict__ Ht, u16* __restrict__ Lt,
    int K, int N)
{
    int idx = blockIdx.x * 256 + threadIdx.x;
    if (idx >= N * K) return;
    int n = idx / K, k = idx - n * K;
    float f = W[(size_t)k * N + n];
    u16 h = f2bf(f);
    u16 l = f2bf(f - bf2f(h));
    Ht[idx] = h;
    Lt[idx] = l;
}

// ---------------- split-bf16 MFMA GEMM ----------------
#define BM 128
#define BN 128
#define BKK 32
#define PK 40   // padded LDS K-stride

#define OUT_F32   0
#define OUT_PAIR  1
#define OUT_PAIRT 2   // v: row->(b=row/77, si), store [(b*512+col)*96 + si]

template<bool APAIR, bool BIAS, int OUTM>
__global__ __launch_bounds__(256) void gemm_split(
    const void* __restrict__ Aptr, const u16* __restrict__ Alptr,
    const u16* __restrict__ Bh, const u16* __restrict__ Bl,
    const float* __restrict__ bias, float* __restrict__ C,
    u16* __restrict__ CH, u16* __restrict__ CL,
    int M, int N, int K)
{
    __shared__ u16 lAh[BM * PK];
    __shared__ u16 lAl[BM * PK];
    __shared__ u16 lBh[BN * PK];
    __shared__ u16 lBl[BN * PK];

    const int t = threadIdx.x;
    const int lane = t & 63;
    const int wid = t >> 6;
    const int wr = wid >> 1, wc = wid & 1;
    const int m0 = blockIdx.x * BM, n0 = blockIdx.y * BN;
    const int ar = lane & 15;
    const int kc = (lane >> 4) << 3;

    f32x4 acc[4][4] = {};

    for (int k0 = 0; k0 < K; k0 += BKK) {
        if constexpr (!APAIR) {
            const float* A = (const float*)Aptr;
            #pragma unroll
            for (int it = 0; it < 4; ++it) {
                int idx = t + it * 256;
                int row = idx >> 3;
                int c4 = (idx & 7) << 2;
                int gr = m0 + row;
                float4 v = make_float4(0.f, 0.f, 0.f, 0.f);
                if (gr < M) v = *(const float4*)(A + (size_t)gr * K + k0 + c4);
                u16 h0 = f2bf(v.x), h1 = f2bf(v.y), h2 = f2bf(v.z), h3 = f2bf(v.w);
                u16 l0 = f2bf(v.x - bf2f(h0));
                u16 l1 = f2bf(v.y - bf2f(h1));
                u16 l2 = f2bf(v.z - bf2f(h2));
                u16 l3 = f2bf(v.w - bf2f(h3));
                *(u16x4*)(lAh + row * PK + c4) = (u16x4){h0, h1, h2, h3};
                *(u16x4*)(lAl + row * PK + c4) = (u16x4){l0, l1, l2, l3};
            }
        } else {
            const u16* Ah = (const u16*)Aptr;
            #pragma unroll
            for (int it = 0; it < 2; ++it) {
                int idx = t + it * 256;
                int row = idx >> 2;
                int c8 = (idx & 3) << 3;
                int gr = m0 + row;
                short8 vh = {0, 0, 0, 0, 0, 0, 0, 0};
                short8 vl = {0, 0, 0, 0, 0, 0, 0, 0};
                if (gr < M) {
                    vh = *(const short8*)(Ah + (size_t)gr * K + k0 + c8);
                    vl = *(const short8*)(Alptr + (size_t)gr * K + k0 + c8);
                }
                *(short8*)(lAh + row * PK + c8) = vh;
                *(short8*)(lAl + row * PK + c8) = vl;
            }
        }
        #pragma unroll
        for (int it = 0; it < 2; ++it) {
            int idx = t + it * 256;
            int row = idx >> 2;
            int c8 = (idx & 3) << 3;
            *(short8*)(lBh + row * PK + c8) =
                *(const short8*)(Bh + (size_t)(n0 + row) * K + k0 + c8);
            *(short8*)(lBl + row * PK + c8) =
                *(const short8*)(Bl + (size_t)(n0 + row) * K + k0 + c8);
        }
        __syncthreads();

        short8 fah[4], fal[4], fbh[4], fbl[4];
        #pragma unroll
        for (int m = 0; m < 4; ++m) {
            fah[m] = *(const short8*)(lAh + (wr * 64 + m * 16 + ar) * PK + kc);
            fal[m] = *(const short8*)(lAl + (wr * 64 + m * 16 + ar) * PK + kc);
        }
        #pragma unroll
        for (int n = 0; n < 4; ++n) {
            fbh[n] = *(const short8*)(lBh + (wc * 64 + n * 16 + ar) * PK + kc);
            fbl[n] = *(const short8*)(lBl + (wc * 64 + n * 16 + ar) * PK + kc);
        }
        #pragma unroll
        for (int m = 0; m < 4; ++m) {
            #pragma unroll
            for (int n = 0; n < 4; ++n) {
                acc[m][n] = mfma16(fah[m], fbh[n], acc[m][n]);
                acc[m][n] = mfma16(fah[m], fbl[n], acc[m][n]);
                acc[m][n] = mfma16(fal[m], fbh[n], acc[m][n]);
            }
        }
        __syncthreads();
    }

    #pragma unroll
    for (int n = 0; n < 4; ++n) {
        int col = n0 + wc * 64 + n * 16 + (lane & 15);
        float bv = 0.f;
        if constexpr (BIAS) bv = bias[col];
        #pragma unroll
        for (int m = 0; m < 4; ++m) {
            #pragma unroll
            for (int r = 0; r < 4; ++r) {
                int row = m0 + wr * 64 + m * 16 + ((lane >> 4) << 2) + r;
                if (row < M) {
                    float v = acc[m][n][r] + bv;
                    if constexpr (OUTM == OUT_F32) {
                        C[(size_t)row * N + col] = v;
                    } else if constexpr (OUTM == OUT_PAIR) {
                        u16 h = f2bf(v);
                        CH[(size_t)row * N + col] = h;
                        CL[(size_t)row * N + col] = f2bf(v - bf2f(h));
                    } else {
                        int bb = row / 77;
                        int si = row - bb * 77;
                        size_t o = ((size_t)bb * 512 + col) * 96 + si;
                        u16 h = f2bf(v);
                        CH[o] = h;
                        CL[o] = f2bf(v - bf2f(h));
                    }
                }
            }
        }
    }
}

// ---------------- MFMA attention ----------------
// grid (Sq/128, H, B), block 256 (4 waves, 32 q-rows each).
// scores = Q Kt (3-pass split), in-reg softmax, P via LDS, PV (3-pass split).
__global__ __launch_bounds__(256) void attn_mfma(
    const u16* __restrict__ qh, const u16* __restrict__ ql,
    const u16* __restrict__ kh, const u16* __restrict__ kl,
    const u16* __restrict__ vTh, const u16* __restrict__ vTl,
    u16* __restrict__ outH, u16* __restrict__ outL)
{
    constexpr int PST = 104;   // P LDS stride: 16B-aligned rows, 2-way banks only
    __shared__ u16 sPh[4 * 32 * PST];
    __shared__ u16 sPl[4 * 32 * PST];

    const int t = threadIdx.x;
    const int lane = t & 63;
    const int w = t >> 6;
    const int ar = lane & 15;
    const int kg = lane >> 4;
    const int kc = kg << 3;
    const int b = blockIdx.z, head = blockIdx.y;
    const size_t qrow0 = (size_t)b * 4096 + blockIdx.x * 128 + w * 32;

    // ---- phase 1: scores [32 q][80 si], K-dim = 64 ----
    f32x4 accs[2][5] = {};
    #pragma unroll
    for (int ks = 0; ks < 2; ++ks) {
        const int d = head * 64 + ks * 32 + kc;
        short8 ah[2], al[2];
        #pragma unroll
        for (int m = 0; m < 2; ++m) {
            size_t o = (qrow0 + m * 16 + ar) * 512 + d;
            ah[m] = *(const short8*)(qh + o);
            al[m] = *(const short8*)(ql + o);
        }
        #pragma unroll
        for (int n = 0; n < 5; ++n) {
            size_t o = ((size_t)(b * 77 + n * 16 + ar)) * 512 + d;  // rows >=1232 padded
            short8 bh = *(const short8*)(kh + o);
            short8 bl = *(const short8*)(kl + o);
            #pragma unroll
            for (int m = 0; m < 2; ++m) {
                accs[m][n] = mfma16(ah[m], bh, accs[m][n]);
                accs[m][n] = mfma16(ah[m], bl, accs[m][n]);
                accs[m][n] = mfma16(al[m], bh, accs[m][n]);
            }
        }
    }

    // ---- softmax in registers; rows live on 16-lane groups ----
    #pragma unroll
    for (int m = 0; m < 2; ++m) {
        #pragma unroll
        for (int r = 0; r < 4; ++r) {
            float mx = -1e30f;
            #pragma unroll
            for (int n = 0; n < 5; ++n) {
                float v = accs[m][n][r] * 0.125f;          // * D_HEAD^-0.5
                if (n == 4 && ar >= 13) v = -1e30f;        // mask si >= 77
                accs[m][n][r] = v;
                mx = fmaxf(mx, v);
            }
            mx = fmaxf(mx, __shfl_xor(mx, 1));
            mx = fmaxf(mx, __shfl_xor(mx, 2));
            mx = fmaxf(mx, __shfl_xor(mx, 4));
            mx = fmaxf(mx, __shfl_xor(mx, 8));
            float sum = 0.f;
            #pragma unroll
            for (int n = 0; n < 5; ++n) {
                float e = __expf(accs[m][n][r] - mx);
                accs[m][n][r] = e;
                sum += e;
            }
            sum += __shfl_xor(sum, 1);
            sum += __shfl_xor(sum, 2);
            sum += __shfl_xor(sum, 4);
            sum += __shfl_xor(sum, 8);
            float inv = 1.f / sum;
            #pragma unroll
            for (int n = 0; n < 5; ++n) accs[m][n][r] *= inv;
        }
    }

    // ---- P -> LDS (split pair), zero-pad cols 80..103 ----
    u16* myPh = sPh + w * 32 * PST;
    u16* myPl = sPl + w * 32 * PST;
    for (int i = lane; i < 32 * 12; i += 64) {
        int row = i / 12, c = 80 + (i % 12) * 2;
        *(u32*)(myPh + row * PST + c) = 0;
        *(u32*)(myPl + row * PST + c) = 0;
    }
    #pragma unroll
    for (int m = 0; m < 2; ++m) {
        #pragma unroll
        for (int n = 0; n < 5; ++n) {
            #pragma unroll
            for (int r = 0; r < 4; ++r) {
                int row = m * 16 + kg * 4 + r;
                int col = n * 16 + ar;
                float v = accs[m][n][r];
                u16 h = f2bf(v);
                myPh[row * PST + col] = h;
                myPl[row * PST + col] = f2bf(v - bf2f(h));
            }
        }
    }
    __syncthreads();

    // ---- phase 2: PV [32 q][64 d], K-dim = 96 (zero-padded) ----
    f32x4 accp[2][4] = {};
    #pragma unroll
    for (int ks = 0; ks < 3; ++ks) {
        short8 pah[2], pal[2];
        #pragma unroll
        for (int m = 0; m < 2; ++m) {
            int o = (m * 16 + ar) * PST + ks * 32 + kc;
            pah[m] = *(const short8*)(myPh + o);
            pal[m] = *(const short8*)(myPl + o);
        }
        #pragma unroll
        for (int n = 0; n < 4; ++n) {
            size_t o = ((size_t)b * 512 + head * 64 + n * 16 + ar) * 96 + ks * 32 + kc;
            short8 bh = *(const short8*)(vTh + o);
            short8 bl = *(const short8*)(vTl + o);
            #pragma unroll
            for (int m = 0; m < 2; ++m) {
                accp[m][n] = mfma16(pah[m], bh, accp[m][n]);
                accp[m][n] = mfma16(pah[m], bl, accp[m][n]);
                accp[m][n] = mfma16(pal[m], bh, accp[m][n]);
            }
        }
    }

    // ---- store attn output as split pair ----
    #pragma unroll
    for (int m = 0; m < 2; ++m) {
        #pragma unroll
        for (int n = 0; n < 4; ++n) {
            #pragma unroll
            for (int r = 0; r < 4; ++r) {
                size_t row = qrow0 + m * 16 + kg * 4 + r;
                int col = head * 64 + n * 16 + ar;
                float v = accp[m][n][r];
                u16 h = f2bf(v);
                outH[row * 512 + col] = h;
                outL[row * 512 + col] = f2bf(v - bf2f(h));
            }
        }
    }
}

extern "C" void kernel_launch(void* const* d_in, const int* in_sizes, int n_in,
                              void* d_out, int out_size, void* d_ws, size_t ws_size,
                              hipStream_t stream)
{
    const float* x    = (const float*)d_in[0];   // [16,4096,512]
    const float* ctx  = (const float*)d_in[1];   // [16,77,768]
    const float* Wq   = (const float*)d_in[2];   // [512,512]
    const float* Wk   = (const float*)d_in[3];   // [768,512]
    const float* Wv   = (const float*)d_in[4];   // [768,512]
    const float* Wout = (const float*)d_in[5];   // [512,512]
    const float* bout = (const float*)d_in[6];   // [512]

    char* ws = (char*)d_ws;
    size_t off = 0;
    auto alloc = [&](size_t bytes) -> void* {
        void* p = ws + off;
        off += (bytes + 255) & ~(size_t)255;
        return p;
    };
    u16* WqH = (u16*)alloc(512 * 512 * 2);
    u16* WqL = (u16*)alloc(512 * 512 * 2);
    u16* WkH = (u16*)alloc(768 * 512 * 2);
    u16* WkL = (u16*)alloc(768 * 512 * 2);
    u16* WvH = (u16*)alloc(768 * 512 * 2);
    u16* WvL = (u16*)alloc(768 * 512 * 2);
    u16* WoH = (u16*)alloc(512 * 512 * 2);
    u16* WoL = (u16*)alloc(512 * 512 * 2);
    u16* kH  = (u16*)alloc((size_t)1240 * 512 * 2);      // 1232 rows + pad
    u16* kL  = (u16*)alloc((size_t)1240 * 512 * 2);
    u16* vTh = (u16*)alloc((size_t)16 * 512 * 96 * 2);   // [b][col][si pad 96]
    u16* vTl = (u16*)alloc((size_t)16 * 512 * 96 * 2);
    u16* attnH = (u16*)alloc((size_t)65536 * 512 * 2);
    u16* attnL = (u16*)alloc((size_t)65536 * 512 * 2);
    (void)ws_size; (void)in_sizes; (void)n_in; (void)out_size;

    // q split pair lives in d_out (exactly 128 MiB), consumed before out-proj
    u16* qH = (u16*)d_out;
    u16* qL = qH + (size_t)65536 * 512;

    // zero Vt pads + k pad rows
    hipMemsetAsync(vTh, 0, (size_t)16 * 512 * 96 * 2, stream);
    hipMemsetAsync(vTl, 0, (size_t)16 * 512 * 96 * 2, stream);
    hipMemsetAsync(kH + (size_t)1232 * 512, 0, (size_t)8 * 512 * 2, stream);
    hipMemsetAsync(kL + (size_t)1232 * 512, 0, (size_t)8 * 512 * 2, stream);

    // 1. weight splits (transposed)
    transpose_split<<<dim3(1024), dim3(256), 0, stream>>>(Wq, WqH, WqL, 512, 512);
    transpose_split<<<dim3(1536), dim3(256), 0, stream>>>(Wk, WkH, WkL, 768, 512);
    transpose_split<<<dim3(1536), dim3(256), 0, stream>>>(Wv, WvH, WvL, 768, 512);
    transpose_split<<<dim3(1024), dim3(256), 0, stream>>>(Wout, WoH, WoL, 512, 512);

    // 2. k/v projections
    gemm_split<false, false, OUT_PAIR><<<dim3(10, 4), dim3(256), 0, stream>>>(
        (const void*)ctx, (const u16*)nullptr, WkH, WkL, (const float*)nullptr,
        (float*)nullptr, kH, kL, 1232, 512, 768);
    gemm_split<false, false, OUT_PAIRT><<<dim3(10, 4), dim3(256), 0, stream>>>(
        (const void*)ctx, (const u16*)nullptr, WvH, WvL, (const float*)nullptr,
        (float*)nullptr, vTh, vTl, 1232, 512, 768);

    // 3. q projection -> split pair in d_out
    gemm_split<false, false, OUT_PAIR><<<dim3(512, 4), dim3(256), 0, stream>>>(
        (const void*)x, (const u16*)nullptr, WqH, WqL, (const float*)nullptr,
        (float*)nullptr, qH, qL, 65536, 512, 512);

    // 4. attention
    attn_mfma<<<dim3(32, 8, 16), dim3(256), 0, stream>>>(
        qH, qL, kH, kL, vTh, vTl, attnH, attnL);

    // 5. output projection + bias
    gemm_split<true, true, OUT_F32><<<dim3(512, 4), dim3(256), 0, stream>>>(
        (const void*)attnH, attnL, WoH, WoL, bout,
        (float*)d_out, (u16*)nullptr, (u16*)nullptr, 65536, 512, 512);
}

// Round 3
// 614.029 us; speedup vs baseline: 1.4397x; 1.0161x over previous
//
#include <hip/hip_runtime.h>

// CrossAttention: B=16, Sq=4096, Dm=512, Skv=77, Dc=768, H=8, Dh=64, inner=512
// Pipeline (all GEMMs 3-pass split-bf16 MFMA ~= fp32):
//   0. split_x  : x fp32 -> hi/lo bf16 pair                                 (ws, reused)
//   1. transpose_split: W* fp32 [K][N] -> hi/lo bf16 [N][K]                 (ws)
//   2. gemm_split OUT_PAIR : k = ctx@Wk -> pair [1240pad][512]              (ws)
//      gemm_split OUT_PAIRT: v = ctx@Wv -> Vt pair [16][512][96pad]         (ws)
//   3. gemm_pair OUT_PAIR : q = xpair@Wq -> pair [65536][512]               (d_out)
//   4. attn_mfma: MFMA scores + in-reg softmax + MFMA PV -> pair            (ws, overwrites xpair)
//   5. gemm_pair OUT_F32+bias: out = attnpair@Wout + bout -> fp32           (d_out)
// Big GEMMs use global_load_lds width-16 staging (m97 recipe), linear LDS.

typedef unsigned short u16;
typedef unsigned int u32;
typedef __attribute__((ext_vector_type(8))) short short8;
typedef __attribute__((ext_vector_type(4))) float f32x4;
typedef __attribute__((ext_vector_type(4))) u16 u16x4;

__device__ __forceinline__ u16 f2bf(float f) {
    union { float f; u32 u; } c; c.f = f;
    u32 r = (c.u + 0x7FFFu + ((c.u >> 16) & 1u)) >> 16;   // RNE
    return (u16)r;
}
__device__ __forceinline__ float bf2f(u16 u) {
    union { u32 u; float f; } c; c.u = ((u32)u) << 16;
    return c.f;
}
__device__ __forceinline__ f32x4 mfma16(short8 a, short8 b, f32x4 c) {
    return __builtin_amdgcn_mfma_f32_16x16x32_bf16(a, b, c, 0, 0, 0);
}
// async global->LDS, 16B per lane; LDS dest = wave-uniform base + lane*16
__device__ __forceinline__ void gl_lds16(const u16* g, u16* l) {
    __builtin_amdgcn_global_load_lds(
        (const __attribute__((address_space(1))) void*)g,
        (__attribute__((address_space(3))) void*)l, 16, 0, 0);
}

// ---------------- x split (elementwise) ----------------
__global__ __launch_bounds__(256) void split_x(
    const float* __restrict__ x, u16* __restrict__ xh, u16* __restrict__ xl, int n4)
{
    int i = blockIdx.x * 256 + threadIdx.x;
    const int stride = gridDim.x * 256;
    for (; i < n4; i += stride) {
        float4 v = ((const float4*)x)[i];
        u16 h0 = f2bf(v.x), h1 = f2bf(v.y), h2 = f2bf(v.z), h3 = f2bf(v.w);
        u16 l0 = f2bf(v.x - bf2f(h0));
        u16 l1 = f2bf(v.y - bf2f(h1));
        u16 l2 = f2bf(v.z - bf2f(h2));
        u16 l3 = f2bf(v.w - bf2f(h3));
        ((u16x4*)xh)[i] = (u16x4){h0, h1, h2, h3};
        ((u16x4*)xl)[i] = (u16x4){l0, l1, l2, l3};
    }
}

// ---------------- weight transpose + split ----------------
__global__ __launch_bounds__(256) void transpose_split(
    const float* __restrict__ W, u16* __restrict__ Ht, u16* __restrict__ Lt,
    int K, int N)
{
    int idx = blockIdx.x * 256 + threadIdx.x;
    if (idx >= N * K) return;
    int n = idx / K, k = idx - n * K;
    float f = W[(size_t)k * N + n];
    u16 h = f2bf(f);
    u16 l = f2bf(f - bf2f(h));
    Ht[idx] = h;
    Lt[idx] = l;
}

#define OUT_F32   0
#define OUT_PAIR  1
#define OUT_PAIRT 2

// ---------------- big split GEMM: pair inputs, global_load_lds staging ----
// A pair [M][K], B pair [N][K]; M,N multiples of 128, K multiple of 32.
template<bool BIAS, int OUTM>
__global__ __launch_bounds__(256) void gemm_pair(
    const u16* __restrict__ Ah, const u16* __restrict__ Al,
    const u16* __restrict__ Bh, const u16* __restrict__ Bl,
    const float* __restrict__ bias, float* __restrict__ C,
    u16* __restrict__ CH, u16* __restrict__ CL,
    int M, int N, int K)
{
    __shared__ u16 lAh[128 * 32];
    __shared__ u16 lAl[128 * 32];
    __shared__ u16 lBh[128 * 32];
    __shared__ u16 lBl[128 * 32];

    const int t = threadIdx.x;
    const int lane = t & 63;
    const int w = t >> 6;
    const int wr = w >> 1, wc = w & 1;           // 2x2 waves of 64x64
    const int m0 = blockIdx.x * 128, n0 = blockIdx.y * 128;
    const int ar = lane & 15;
    const int kc = (lane >> 4) << 3;
    const int srow = lane >> 2;                  // staging: row within 16-row chunk
    const int scol = (lane & 3) << 3;            // staging: u16 col 0/8/16/24

    f32x4 acc[4][4] = {};

    for (int k0 = 0; k0 < K; k0 += 32) {
        // ---- stage 4 tiles via global_load_lds (8 chunks x 1024B each) ----
        #pragma unroll
        for (int j = 0; j < 2; ++j) {
            const int ci = w * 2 + j;            // chunk id 0..7 -> rows ci*16..+15
            const int r = ci * 16 + srow;
            const size_t ga = (size_t)(m0 + r) * K + k0 + scol;
            const size_t gb = (size_t)(n0 + r) * K + k0 + scol;
            gl_lds16(Ah + ga, lAh + ci * 512);
            gl_lds16(Al + ga, lAl + ci * 512);
            gl_lds16(Bh + gb, lBh + ci * 512);
            gl_lds16(Bl + gb, lBl + ci * 512);
        }
        __syncthreads();

        short8 fah[4], fal[4], fbh[4], fbl[4];
        #pragma unroll
        for (int m = 0; m < 4; ++m) {
            fah[m] = *(const short8*)(lAh + (wr * 64 + m * 16 + ar) * 32 + kc);
            fal[m] = *(const short8*)(lAl + (wr * 64 + m * 16 + ar) * 32 + kc);
        }
        #pragma unroll
        for (int n = 0; n < 4; ++n) {
            fbh[n] = *(const short8*)(lBh + (wc * 64 + n * 16 + ar) * 32 + kc);
            fbl[n] = *(const short8*)(lBl + (wc * 64 + n * 16 + ar) * 32 + kc);
        }
        #pragma unroll
        for (int m = 0; m < 4; ++m) {
            #pragma unroll
            for (int n = 0; n < 4; ++n) {
                acc[m][n] = mfma16(fah[m], fbh[n], acc[m][n]);
                acc[m][n] = mfma16(fah[m], fbl[n], acc[m][n]);
                acc[m][n] = mfma16(fal[m], fbh[n], acc[m][n]);
            }
        }
        __syncthreads();
    }

    #pragma unroll
    for (int n = 0; n < 4; ++n) {
        int col = n0 + wc * 64 + n * 16 + ar;
        float bv = 0.f;
        if constexpr (BIAS) bv = bias[col];
        #pragma unroll
        for (int m = 0; m < 4; ++m) {
            #pragma unroll
            for (int r = 0; r < 4; ++r) {
                int row = m0 + wr * 64 + m * 16 + ((lane >> 4) << 2) + r;
                float v = acc[m][n][r] + bv;
                if constexpr (OUTM == OUT_F32) {
                    C[(size_t)row * N + col] = v;
                } else {
                    u16 h = f2bf(v);
                    CH[(size_t)row * N + col] = h;
                    CL[(size_t)row * N + col] = f2bf(v - bf2f(h));
                }
            }
        }
    }
}

// ---------------- small split GEMM (kv projections, reg-staged) ----------------
#define BM 128
#define BN 128
#define PK 40

template<bool BIAS, int OUTM>
__global__ __launch_bounds__(256) void gemm_split(
    const float* __restrict__ A,
    const u16* __restrict__ Bh, const u16* __restrict__ Bl,
    const float* __restrict__ bias, float* __restrict__ C,
    u16* __restrict__ CH, u16* __restrict__ CL,
    int M, int N, int K)
{
    __shared__ u16 lAh[BM * PK];
    __shared__ u16 lAl[BM * PK];
    __shared__ u16 lBh[BN * PK];
    __shared__ u16 lBl[BN * PK];

    const int t = threadIdx.x;
    const int lane = t & 63;
    const int wid = t >> 6;
    const int wr = wid >> 1, wc = wid & 1;
    const int m0 = blockIdx.x * BM, n0 = blockIdx.y * BN;
    const int ar = lane & 15;
    const int kc = (lane >> 4) << 3;

    f32x4 acc[4][4] = {};

    for (int k0 = 0; k0 < K; k0 += 32) {
        #pragma unroll
        for (int it = 0; it < 4; ++it) {
            int idx = t + it * 256;
            int row = idx >> 3;
            int c4 = (idx & 7) << 2;
            int gr = m0 + row;
            float4 v = make_float4(0.f, 0.f, 0.f, 0.f);
            if (gr < M) v = *(const float4*)(A + (size_t)gr * K + k0 + c4);
            u16 h0 = f2bf(v.x), h1 = f2bf(v.y), h2 = f2bf(v.z), h3 = f2bf(v.w);
            u16 l0 = f2bf(v.x - bf2f(h0));
            u16 l1 = f2bf(v.y - bf2f(h1));
            u16 l2 = f2bf(v.z - bf2f(h2));
            u16 l3 = f2bf(v.w - bf2f(h3));
            *(u16x4*)(lAh + row * PK + c4) = (u16x4){h0, h1, h2, h3};
            *(u16x4*)(lAl + row * PK + c4) = (u16x4){l0, l1, l2, l3};
        }
        #pragma unroll
        for (int it = 0; it < 2; ++it) {
            int idx = t + it * 256;
            int row = idx >> 2;
            int c8 = (idx & 3) << 3;
            *(short8*)(lBh + row * PK + c8) =
                *(const short8*)(Bh + (size_t)(n0 + row) * K + k0 + c8);
            *(short8*)(lBl + row * PK + c8) =
                *(const short8*)(Bl + (size_t)(n0 + row) * K + k0 + c8);
        }
        __syncthreads();

        short8 fah[4], fal[4], fbh[4], fbl[4];
        #pragma unroll
        for (int m = 0; m < 4; ++m) {
            fah[m] = *(const short8*)(lAh + (wr * 64 + m * 16 + ar) * PK + kc);
            fal[m] = *(const short8*)(lAl + (wr * 64 + m * 16 + ar) * PK + kc);
        }
        #pragma unroll
        for (int n = 0; n < 4; ++n) {
            fbh[n] = *(const short8*)(lBh + (wc * 64 + n * 16 + ar) * PK + kc);
            fbl[n] = *(const short8*)(lBl + (wc * 64 + n * 16 + ar) * PK + kc);
        }
        #pragma unroll
        for (int m = 0; m < 4; ++m) {
            #pragma unroll
            for (int n = 0; n < 4; ++n) {
                acc[m][n] = mfma16(fah[m], fbh[n], acc[m][n]);
                acc[m][n] = mfma16(fah[m], fbl[n], acc[m][n]);
                acc[m][n] = mfma16(fal[m], fbh[n], acc[m][n]);
            }
        }
        __syncthreads();
    }

    #pragma unroll
    for (int n = 0; n < 4; ++n) {
        int col = n0 + wc * 64 + n * 16 + ar;
        float bv = 0.f;
        if constexpr (BIAS) bv = bias[col];
        #pragma unroll
        for (int m = 0; m < 4; ++m) {
            #pragma unroll
            for (int r = 0; r < 4; ++r) {
                int row = m0 + wr * 64 + m * 16 + ((lane >> 4) << 2) + r;
                if (row < M) {
                    float v = acc[m][n][r] + bv;
                    if constexpr (OUTM == OUT_F32) {
                        C[(size_t)row * N + col] = v;
                    } else if constexpr (OUTM == OUT_PAIR) {
                        u16 h = f2bf(v);
                        CH[(size_t)row * N + col] = h;
                        CL[(size_t)row * N + col] = f2bf(v - bf2f(h));
                    } else {
                        int bb = row / 77;
                        int si = row - bb * 77;
                        size_t o = ((size_t)bb * 512 + col) * 96 + si;
                        u16 h = f2bf(v);
                        CH[o] = h;
                        CL[o] = f2bf(v - bf2f(h));
                    }
                }
            }
        }
    }
}

// ---------------- MFMA attention ----------------
__global__ __launch_bounds__(256) void attn_mfma(
    const u16* __restrict__ qh, const u16* __restrict__ ql,
    const u16* __restrict__ kh, const u16* __restrict__ kl,
    const u16* __restrict__ vTh, const u16* __restrict__ vTl,
    u16* __restrict__ outH, u16* __restrict__ outL)
{
    constexpr int PST = 104;
    __shared__ u16 sPh[4 * 32 * PST];
    __shared__ u16 sPl[4 * 32 * PST];

    const int t = threadIdx.x;
    const int lane = t & 63;
    const int w = t >> 6;
    const int ar = lane & 15;
    const int kg = lane >> 4;
    const int kc = kg << 3;
    const int b = blockIdx.z, head = blockIdx.y;
    const size_t qrow0 = (size_t)b * 4096 + blockIdx.x * 128 + w * 32;

    f32x4 accs[2][5] = {};
    #pragma unroll
    for (int ks = 0; ks < 2; ++ks) {
        const int d = head * 64 + ks * 32 + kc;
        short8 ah[2], al[2];
        #pragma unroll
        for (int m = 0; m < 2; ++m) {
            size_t o = (qrow0 + m * 16 + ar) * 512 + d;
            ah[m] = *(const short8*)(qh + o);
            al[m] = *(const short8*)(ql + o);
        }
        #pragma unroll
        for (int n = 0; n < 5; ++n) {
            size_t o = ((size_t)(b * 77 + n * 16 + ar)) * 512 + d;
            short8 bh = *(const short8*)(kh + o);
            short8 bl = *(const short8*)(kl + o);
            #pragma unroll
            for (int m = 0; m < 2; ++m) {
                accs[m][n] = mfma16(ah[m], bh, accs[m][n]);
                accs[m][n] = mfma16(ah[m], bl, accs[m][n]);
                accs[m][n] = mfma16(al[m], bh, accs[m][n]);
            }
        }
    }

    #pragma unroll
    for (int m = 0; m < 2; ++m) {
        #pragma unroll
        for (int r = 0; r < 4; ++r) {
            float mx = -1e30f;
            #pragma unroll
            for (int n = 0; n < 5; ++n) {
                float v = accs[m][n][r] * 0.125f;
                if (n == 4 && ar >= 13) v = -1e30f;
                accs[m][n][r] = v;
                mx = fmaxf(mx, v);
            }
            mx = fmaxf(mx, __shfl_xor(mx, 1));
            mx = fmaxf(mx, __shfl_xor(mx, 2));
            mx = fmaxf(mx, __shfl_xor(mx, 4));
            mx = fmaxf(mx, __shfl_xor(mx, 8));
            float sum = 0.f;
            #pragma unroll
            for (int n = 0; n < 5; ++n) {
                float e = __expf(accs[m][n][r] - mx);
                accs[m][n][r] = e;
                sum += e;
            }
            sum += __shfl_xor(sum, 1);
            sum += __shfl_xor(sum, 2);
            sum += __shfl_xor(sum, 4);
            sum += __shfl_xor(sum, 8);
            float inv = 1.f / sum;
            #pragma unroll
            for (int n = 0; n < 5; ++n) accs[m][n][r] *= inv;
        }
    }

    u16* myPh = sPh + w * 32 * PST;
    u16* myPl = sPl + w * 32 * PST;
    for (int i = lane; i < 32 * 12; i += 64) {
        int row = i / 12, c = 80 + (i % 12) * 2;
        *(u32*)(myPh + row * PST + c) = 0;
        *(u32*)(myPl + row * PST + c) = 0;
    }
    #pragma unroll
    for (int m = 0; m < 2; ++m) {
        #pragma unroll
        for (int n = 0; n < 5; ++n) {
            #pragma unroll
            for (int r = 0; r < 4; ++r) {
                int row = m * 16 + kg * 4 + r;
                int col = n * 16 + ar;
                float v = accs[m][n][r];
                u16 h = f2bf(v);
                myPh[row * PST + col] = h;
                myPl[row * PST + col] = f2bf(v - bf2f(h));
            }
        }
    }
    __syncthreads();

    f32x4 accp[2][4] = {};
    #pragma unroll
    for (int ks = 0; ks < 3; ++ks) {
        short8 pah[2], pal[2];
        #pragma unroll
        for (int m = 0; m < 2; ++m) {
            int o = (m * 16 + ar) * PST + ks * 32 + kc;
            pah[m] = *(const short8*)(myPh + o);
            pal[m] = *(const short8*)(myPl + o);
        }
        #pragma unroll
        for (int n = 0; n < 4; ++n) {
            size_t o = ((size_t)b * 512 + head * 64 + n * 16 + ar) * 96 + ks * 32 + kc;
            short8 bh = *(const short8*)(vTh + o);
            short8 bl = *(const short8*)(vTl + o);
            #pragma unroll
            for (int m = 0; m < 2; ++m) {
                accp[m][n] = mfma16(pah[m], bh, accp[m][n]);
                accp[m][n] = mfma16(pah[m], bl, accp[m][n]);
                accp[m][n] = mfma16(pal[m], bh, accp[m][n]);
            }
        }
    }

    #pragma unroll
    for (int m = 0; m < 2; ++m) {
        #pragma unroll
        for (int n = 0; n < 4; ++n) {
            #pragma unroll
            for (int r = 0; r < 4; ++r) {
                size_t row = qrow0 + m * 16 + kg * 4 + r;
                int col = head * 64 + n * 16 + ar;
                float v = accp[m][n][r];
                u16 h = f2bf(v);
                outH[row * 512 + col] = h;
                outL[row * 512 + col] = f2bf(v - bf2f(h));
            }
        }
    }
}

extern "C" void kernel_launch(void* const* d_in, const int* in_sizes, int n_in,
                              void* d_out, int out_size, void* d_ws, size_t ws_size,
                              hipStream_t stream)
{
    const float* x    = (const float*)d_in[0];   // [16,4096,512]
    const float* ctx  = (const float*)d_in[1];   // [16,77,768]
    const float* Wq   = (const float*)d_in[2];   // [512,512]
    const float* Wk   = (const float*)d_in[3];   // [768,512]
    const float* Wv   = (const float*)d_in[4];   // [768,512]
    const float* Wout = (const float*)d_in[5];   // [512,512]
    const float* bout = (const float*)d_in[6];   // [512]

    char* ws = (char*)d_ws;
    size_t off = 0;
    auto alloc = [&](size_t bytes) -> void* {
        void* p = ws + off;
        off += (bytes + 255) & ~(size_t)255;
        return p;
    };
    u16* WqH = (u16*)alloc(512 * 512 * 2);
    u16* WqL = (u16*)alloc(512 * 512 * 2);
    u16* WkH = (u16*)alloc(768 * 512 * 2);
    u16* WkL = (u16*)alloc(768 * 512 * 2);
    u16* WvH = (u16*)alloc(768 * 512 * 2);
    u16* WvL = (u16*)alloc(768 * 512 * 2);
    u16* WoH = (u16*)alloc(512 * 512 * 2);
    u16* WoL = (u16*)alloc(512 * 512 * 2);
    u16* kH  = (u16*)alloc((size_t)1240 * 512 * 2);
    u16* kL  = (u16*)alloc((size_t)1240 * 512 * 2);
    u16* vTh = (u16*)alloc((size_t)16 * 512 * 96 * 2);
    u16* vTl = (u16*)alloc((size_t)16 * 512 * 96 * 2);
    // 128 MiB block: first holds x pair, later reused for attn pair (x dead by then)
    u16* xH = (u16*)alloc((size_t)65536 * 512 * 2);
    u16* xL = (u16*)alloc((size_t)65536 * 512 * 2);
    u16* attnH = xH;
    u16* attnL = xL;
    (void)ws_size; (void)in_sizes; (void)n_in; (void)out_size;

    // q pair lives in d_out (exactly 128 MiB), dead before final GEMM writes there
    u16* qH = (u16*)d_out;
    u16* qL = qH + (size_t)65536 * 512;

    hipMemsetAsync(vTh, 0, (size_t)16 * 512 * 96 * 2, stream);
    hipMemsetAsync(vTl, 0, (size_t)16 * 512 * 96 * 2, stream);
    hipMemsetAsync(kH + (size_t)1232 * 512, 0, (size_t)8 * 512 * 2, stream);
    hipMemsetAsync(kL + (size_t)1232 * 512, 0, (size_t)8 * 512 * 2, stream);

    // 0. split x -> pair
    split_x<<<dim3(2048), dim3(256), 0, stream>>>(x, xH, xL, 65536 * 512 / 4);

    // 1. weight splits (transposed)
    transpose_split<<<dim3(1024), dim3(256), 0, stream>>>(Wq, WqH, WqL, 512, 512);
    transpose_split<<<dim3(1536), dim3(256), 0, stream>>>(Wk, WkH, WkL, 768, 512);
    transpose_split<<<dim3(1536), dim3(256), 0, stream>>>(Wv, WvH, WvL, 768, 512);
    transpose_split<<<dim3(1024), dim3(256), 0, stream>>>(Wout, WoH, WoL, 512, 512);

    // 2. k/v projections (small, reg-staged)
    gemm_split<false, OUT_PAIR><<<dim3(10, 4), dim3(256), 0, stream>>>(
        ctx, WkH, WkL, (const float*)nullptr,
        (float*)nullptr, kH, kL, 1232, 512, 768);
    gemm_split<false, OUT_PAIRT><<<dim3(10, 4), dim3(256), 0, stream>>>(
        ctx, WvH, WvL, (const float*)nullptr,
        (float*)nullptr, vTh, vTl, 1232, 512, 768);

    // 3. q projection: xpair @ Wq -> q pair in d_out
    gemm_pair<false, OUT_PAIR><<<dim3(512, 4), dim3(256), 0, stream>>>(
        xH, xL, WqH, WqL, (const float*)nullptr,
        (float*)nullptr, qH, qL, 65536, 512, 512);

    // 4. attention -> attn pair (reuses xpair buffer)
    attn_mfma<<<dim3(32, 8, 16), dim3(256), 0, stream>>>(
        qH, qL, kH, kL, vTh, vTl, attnH, attnL);

    // 5. output projection + bias -> d_out
    gemm_pair<true, OUT_F32><<<dim3(512, 4), dim3(256), 0, stream>>>(
        attnH, attnL, WoH, WoL, bout,
        (float*)d_out, (u16*)nullptr, (u16*)nullptr, 65536, 512, 512);
}

// Round 4
// 565.089 us; speedup vs baseline: 1.5643x; 1.0866x over previous
//
#include <hip/hip_runtime.h>

// CrossAttention: B=16, Sq=4096, Dm=512, Skv=77, Dc=768, H=8, Dh=64, inner=512
// Pipeline (all GEMMs 3-pass split-bf16 MFMA ~= fp32):
//   0. split_x  : x fp32 -> hi/lo bf16 pair                                 (ws, reused)
//   1. transpose_split: W* fp32 [K][N] -> hi/lo bf16 [N][K]                 (ws)
//   2. gemm_split OUT_PAIR : k = ctx@Wk -> pair [1240pad][512]              (ws)
//      gemm_split OUT_PAIRT: v = ctx@Wv -> Vt pair [16][512][96pad]         (ws)
//   3. gemm_pair OUT_PAIR : q = xpair@Wq -> pair [65536][512]               (d_out)
//   4. attn_mfma: MFMA scores + in-reg softmax + MFMA PV -> pair            (ws, overwrites xpair)
//   5. gemm_pair OUT_F32+bias: out = attnpair@Wout + bout -> fp32           (d_out)
// gemm_pair: dbuf LDS + issue-early global_load_lds (T3-minimum 2-phase),
//            XCD-chunked swizzle with N-fastest grid for A-tile L2 reuse.

typedef unsigned short u16;
typedef unsigned int u32;
typedef __attribute__((ext_vector_type(8))) short short8;
typedef __attribute__((ext_vector_type(4))) float f32x4;
typedef __attribute__((ext_vector_type(4))) u16 u16x4;

__device__ __forceinline__ u16 f2bf(float f) {
    union { float f; u32 u; } c; c.f = f;
    u32 r = (c.u + 0x7FFFu + ((c.u >> 16) & 1u)) >> 16;   // RNE
    return (u16)r;
}
__device__ __forceinline__ float bf2f(u16 u) {
    union { u32 u; float f; } c; c.u = ((u32)u) << 16;
    return c.f;
}
__device__ __forceinline__ f32x4 mfma16(short8 a, short8 b, f32x4 c) {
    return __builtin_amdgcn_mfma_f32_16x16x32_bf16(a, b, c, 0, 0, 0);
}
// async global->LDS, 16B per lane; LDS dest = wave-uniform base + lane*16
__device__ __forceinline__ void gl_lds16(const u16* g, u16* l) {
    __builtin_amdgcn_global_load_lds(
        (const __attribute__((address_space(1))) void*)g,
        (__attribute__((address_space(3))) void*)l, 16, 0, 0);
}

// ---------------- x split (elementwise) ----------------
__global__ __launch_bounds__(256) void split_x(
    const float* __restrict__ x, u16* __restrict__ xh, u16* __restrict__ xl, int n4)
{
    int i = blockIdx.x * 256 + threadIdx.x;
    const int stride = gridDim.x * 256;
    for (; i < n4; i += stride) {
        float4 v = ((const float4*)x)[i];
        u16 h0 = f2bf(v.x), h1 = f2bf(v.y), h2 = f2bf(v.z), h3 = f2bf(v.w);
        u16 l0 = f2bf(v.x - bf2f(h0));
        u16 l1 = f2bf(v.y - bf2f(h1));
        u16 l2 = f2bf(v.z - bf2f(h2));
        u16 l3 = f2bf(v.w - bf2f(h3));
        ((u16x4*)xh)[i] = (u16x4){h0, h1, h2, h3};
        ((u16x4*)xl)[i] = (u16x4){l0, l1, l2, l3};
    }
}

// ---------------- weight transpose + split ----------------
__global__ __launch_bounds__(256) void transpose_split(
    const float* __restrict__ W, u16* __restrict__ Ht, u16* __restrict__ Lt,
    int K, int N)
{
    int idx = blockIdx.x * 256 + threadIdx.x;
    if (idx >= N * K) return;
    int n = idx / K, k = idx - n * K;
    float f = W[(size_t)k * N + n];
    u16 h = f2bf(f);
    u16 l = f2bf(f - bf2f(h));
    Ht[idx] = h;
    Lt[idx] = l;
}

#define OUT_F32   0
#define OUT_PAIR  1
#define OUT_PAIRT 2

// ---------------- big split GEMM: pair inputs, dbuf + gl_lds staging ----
// A pair [M][K], B pair [N][K]; M,N multiples of 128, K multiple of 32.
// launch grid: dim3(N/128, M/128)  (N fastest for A-sharing locality)
template<bool BIAS, int OUTM>
__global__ __launch_bounds__(256) void gemm_pair(
    const u16* __restrict__ Ah, const u16* __restrict__ Al,
    const u16* __restrict__ Bh, const u16* __restrict__ Bl,
    const float* __restrict__ bias, float* __restrict__ C,
    u16* __restrict__ CH, u16* __restrict__ CL,
    int M, int N, int K)
{
    __shared__ u16 sm[2][4][128 * 32];   // [buf][Ah,Al,Bh,Bl]

    const int t = threadIdx.x;
    const int lane = t & 63;
    const int w = t >> 6;
    const int wr = w >> 1, wc = w & 1;           // 2x2 waves of 64x64

    // XCD-chunked bijective swizzle (nblk % 8 == 0 here: 2048)
    const int f = blockIdx.x + gridDim.x * blockIdx.y;
    const int cpx = (gridDim.x * gridDim.y) >> 3;
    const int logical = (f & 7) * cpx + (f >> 3);
    const int m0 = (logical / gridDim.x) * 128;
    const int n0 = (logical % gridDim.x) * 128;

    const int ar = lane & 15;
    const int kc = (lane >> 4) << 3;
    const int srow = lane >> 2;                  // staging row within 16-row chunk
    const int scol = (lane & 3) << 3;            // staging u16 col 0/8/16/24

    f32x4 acc[4][4] = {};

    auto STAGE = [&](int buf, int k0) {
        #pragma unroll
        for (int j = 0; j < 2; ++j) {
            const int ci = w * 2 + j;            // chunk 0..7 -> rows ci*16..+15
            const int r = ci * 16 + srow;
            const size_t ga = (size_t)(m0 + r) * K + k0 + scol;
            const size_t gb = (size_t)(n0 + r) * K + k0 + scol;
            gl_lds16(Ah + ga, &sm[buf][0][ci * 512]);
            gl_lds16(Al + ga, &sm[buf][1][ci * 512]);
            gl_lds16(Bh + gb, &sm[buf][2][ci * 512]);
            gl_lds16(Bl + gb, &sm[buf][3][ci * 512]);
        }
    };

    const int nk = K >> 5;
    STAGE(0, 0);
    __syncthreads();        // drains vmcnt(0): buf0 ready

    int cur = 0;
    for (int kt = 0; kt < nk; ++kt) {
        // issue next tile's loads early — they fly under ds_read + MFMA
        if (kt + 1 < nk) STAGE(cur ^ 1, (kt + 1) << 5);

        const u16* pAh = sm[cur][0];
        const u16* pAl = sm[cur][1];
        const u16* pBh = sm[cur][2];
        const u16* pBl = sm[cur][3];

        short8 fah[4], fal[4], fbh[4], fbl[4];
        #pragma unroll
        for (int m = 0; m < 4; ++m) {
            fah[m] = *(const short8*)(pAh + (wr * 64 + m * 16 + ar) * 32 + kc);
            fal[m] = *(const short8*)(pAl + (wr * 64 + m * 16 + ar) * 32 + kc);
        }
        #pragma unroll
        for (int n = 0; n < 4; ++n) {
            fbh[n] = *(const short8*)(pBh + (wc * 64 + n * 16 + ar) * 32 + kc);
            fbl[n] = *(const short8*)(pBl + (wc * 64 + n * 16 + ar) * 32 + kc);
        }
        __builtin_amdgcn_s_setprio(1);
        #pragma unroll
        for (int m = 0; m < 4; ++m) {
            #pragma unroll
            for (int n = 0; n < 4; ++n) {
                acc[m][n] = mfma16(fah[m], fbh[n], acc[m][n]);
                acc[m][n] = mfma16(fah[m], fbl[n], acc[m][n]);
                acc[m][n] = mfma16(fal[m], fbh[n], acc[m][n]);
            }
        }
        __builtin_amdgcn_s_setprio(0);
        __syncthreads();    // drains vmcnt(0) + lgkm: next buf staged, cur free
        cur ^= 1;
    }

    #pragma unroll
    for (int n = 0; n < 4; ++n) {
        int col = n0 + wc * 64 + n * 16 + ar;
        float bv = 0.f;
        if constexpr (BIAS) bv = bias[col];
        #pragma unroll
        for (int m = 0; m < 4; ++m) {
            #pragma unroll
            for (int r = 0; r < 4; ++r) {
                int row = m0 + wr * 64 + m * 16 + ((lane >> 4) << 2) + r;
                float v = acc[m][n][r] + bv;
                if constexpr (OUTM == OUT_F32) {
                    C[(size_t)row * N + col] = v;
                } else {
                    u16 h = f2bf(v);
                    CH[(size_t)row * N + col] = h;
                    CL[(size_t)row * N + col] = f2bf(v - bf2f(h));
                }
            }
        }
    }
}

// ---------------- small split GEMM (kv projections, reg-staged) ----------------
#define BM 128
#define BN 128
#define PK 40

template<bool BIAS, int OUTM>
__global__ __launch_bounds__(256) void gemm_split(
    const float* __restrict__ A,
    const u16* __restrict__ Bh, const u16* __restrict__ Bl,
    const float* __restrict__ bias, float* __restrict__ C,
    u16* __restrict__ CH, u16* __restrict__ CL,
    int M, int N, int K)
{
    __shared__ u16 lAh[BM * PK];
    __shared__ u16 lAl[BM * PK];
    __shared__ u16 lBh[BN * PK];
    __shared__ u16 lBl[BN * PK];

    const int t = threadIdx.x;
    const int lane = t & 63;
    const int wid = t >> 6;
    const int wr = wid >> 1, wc = wid & 1;
    const int m0 = blockIdx.x * BM, n0 = blockIdx.y * BN;
    const int ar = lane & 15;
    const int kc = (lane >> 4) << 3;

    f32x4 acc[4][4] = {};

    for (int k0 = 0; k0 < K; k0 += 32) {
        #pragma unroll
        for (int it = 0; it < 4; ++it) {
            int idx = t + it * 256;
            int row = idx >> 3;
            int c4 = (idx & 7) << 2;
            int gr = m0 + row;
            float4 v = make_float4(0.f, 0.f, 0.f, 0.f);
            if (gr < M) v = *(const float4*)(A + (size_t)gr * K + k0 + c4);
            u16 h0 = f2bf(v.x), h1 = f2bf(v.y), h2 = f2bf(v.z), h3 = f2bf(v.w);
            u16 l0 = f2bf(v.x - bf2f(h0));
            u16 l1 = f2bf(v.y - bf2f(h1));
            u16 l2 = f2bf(v.z - bf2f(h2));
            u16 l3 = f2bf(v.w - bf2f(h3));
            *(u16x4*)(lAh + row * PK + c4) = (u16x4){h0, h1, h2, h3};
            *(u16x4*)(lAl + row * PK + c4) = (u16x4){l0, l1, l2, l3};
        }
        #pragma unroll
        for (int it = 0; it < 2; ++it) {
            int idx = t + it * 256;
            int row = idx >> 2;
            int c8 = (idx & 3) << 3;
            *(short8*)(lBh + row * PK + c8) =
                *(const short8*)(Bh + (size_t)(n0 + row) * K + k0 + c8);
            *(short8*)(lBl + row * PK + c8) =
                *(const short8*)(Bl + (size_t)(n0 + row) * K + k0 + c8);
        }
        __syncthreads();

        short8 fah[4], fal[4], fbh[4], fbl[4];
        #pragma unroll
        for (int m = 0; m < 4; ++m) {
            fah[m] = *(const short8*)(lAh + (wr * 64 + m * 16 + ar) * PK + kc);
            fal[m] = *(const short8*)(lAl + (wr * 64 + m * 16 + ar) * PK + kc);
        }
        #pragma unroll
        for (int n = 0; n < 4; ++n) {
            fbh[n] = *(const short8*)(lBh + (wc * 64 + n * 16 + ar) * PK + kc);
            fbl[n] = *(const short8*)(lBl + (wc * 64 + n * 16 + ar) * PK + kc);
        }
        #pragma unroll
        for (int m = 0; m < 4; ++m) {
            #pragma unroll
            for (int n = 0; n < 4; ++n) {
                acc[m][n] = mfma16(fah[m], fbh[n], acc[m][n]);
                acc[m][n] = mfma16(fah[m], fbl[n], acc[m][n]);
                acc[m][n] = mfma16(fal[m], fbh[n], acc[m][n]);
            }
        }
        __syncthreads();
    }

    #pragma unroll
    for (int n = 0; n < 4; ++n) {
        int col = n0 + wc * 64 + n * 16 + ar;
        float bv = 0.f;
        if constexpr (BIAS) bv = bias[col];
        #pragma unroll
        for (int m = 0; m < 4; ++m) {
            #pragma unroll
            for (int r = 0; r < 4; ++r) {
                int row = m0 + wr * 64 + m * 16 + ((lane >> 4) << 2) + r;
                if (row < M) {
                    float v = acc[m][n][r] + bv;
                    if constexpr (OUTM == OUT_F32) {
                        C[(size_t)row * N + col] = v;
                    } else if constexpr (OUTM == OUT_PAIR) {
                        u16 h = f2bf(v);
                        CH[(size_t)row * N + col] = h;
                        CL[(size_t)row * N + col] = f2bf(v - bf2f(h));
                    } else {
                        int bb = row / 77;
                        int si = row - bb * 77;
                        size_t o = ((size_t)bb * 512 + col) * 96 + si;
                        u16 h = f2bf(v);
                        CH[o] = h;
                        CL[o] = f2bf(v - bf2f(h));
                    }
                }
            }
        }
    }
}

// ---------------- MFMA attention ----------------
__global__ __launch_bounds__(256) void attn_mfma(
    const u16* __restrict__ qh, const u16* __restrict__ ql,
    const u16* __restrict__ kh, const u16* __restrict__ kl,
    const u16* __restrict__ vTh, const u16* __restrict__ vTl,
    u16* __restrict__ outH, u16* __restrict__ outL)
{
    constexpr int PST = 104;
    __shared__ u16 sPh[4 * 32 * PST];
    __shared__ u16 sPl[4 * 32 * PST];

    const int t = threadIdx.x;
    const int lane = t & 63;
    const int w = t >> 6;
    const int ar = lane & 15;
    const int kg = lane >> 4;
    const int kc = kg << 3;
    const int b = blockIdx.z, head = blockIdx.y;
    const size_t qrow0 = (size_t)b * 4096 + blockIdx.x * 128 + w * 32;

    f32x4 accs[2][5] = {};
    #pragma unroll
    for (int ks = 0; ks < 2; ++ks) {
        const int d = head * 64 + ks * 32 + kc;
        short8 ah[2], al[2];
        #pragma unroll
        for (int m = 0; m < 2; ++m) {
            size_t o = (qrow0 + m * 16 + ar) * 512 + d;
            ah[m] = *(const short8*)(qh + o);
            al[m] = *(const short8*)(ql + o);
        }
        #pragma unroll
        for (int n = 0; n < 5; ++n) {
            size_t o = ((size_t)(b * 77 + n * 16 + ar)) * 512 + d;
            short8 bh = *(const short8*)(kh + o);
            short8 bl = *(const short8*)(kl + o);
            #pragma unroll
            for (int m = 0; m < 2; ++m) {
                accs[m][n] = mfma16(ah[m], bh, accs[m][n]);
                accs[m][n] = mfma16(ah[m], bl, accs[m][n]);
                accs[m][n] = mfma16(al[m], bh, accs[m][n]);
            }
        }
    }

    #pragma unroll
    for (int m = 0; m < 2; ++m) {
        #pragma unroll
        for (int r = 0; r < 4; ++r) {
            float mx = -1e30f;
            #pragma unroll
            for (int n = 0; n < 5; ++n) {
                float v = accs[m][n][r] * 0.125f;
                if (n == 4 && ar >= 13) v = -1e30f;
                accs[m][n][r] = v;
                mx = fmaxf(mx, v);
            }
            mx = fmaxf(mx, __shfl_xor(mx, 1));
            mx = fmaxf(mx, __shfl_xor(mx, 2));
            mx = fmaxf(mx, __shfl_xor(mx, 4));
            mx = fmaxf(mx, __shfl_xor(mx, 8));
            float sum = 0.f;
            #pragma unroll
            for (int n = 0; n < 5; ++n) {
                float e = __expf(accs[m][n][r] - mx);
                accs[m][n][r] = e;
                sum += e;
            }
            sum += __shfl_xor(sum, 1);
            sum += __shfl_xor(sum, 2);
            sum += __shfl_xor(sum, 4);
            sum += __shfl_xor(sum, 8);
            float inv = 1.f / sum;
            #pragma unroll
            for (int n = 0; n < 5; ++n) accs[m][n][r] *= inv;
        }
    }

    u16* myPh = sPh + w * 32 * PST;
    u16* myPl = sPl + w * 32 * PST;
    for (int i = lane; i < 32 * 12; i += 64) {
        int row = i / 12, c = 80 + (i % 12) * 2;
        *(u32*)(myPh + row * PST + c) = 0;
        *(u32*)(myPl + row * PST + c) = 0;
    }
    #pragma unroll
    for (int m = 0; m < 2; ++m) {
        #pragma unroll
        for (int n = 0; n < 5; ++n) {
            #pragma unroll
            for (int r = 0; r < 4; ++r) {
                int row = m * 16 + kg * 4 + r;
                int col = n * 16 + ar;
                float v = accs[m][n][r];
                u16 h = f2bf(v);
                myPh[row * PST + col] = h;
                myPl[row * PST + col] = f2bf(v - bf2f(h));
            }
        }
    }
    __syncthreads();

    f32x4 accp[2][4] = {};
    #pragma unroll
    for (int ks = 0; ks < 3; ++ks) {
        short8 pah[2], pal[2];
        #pragma unroll
        for (int m = 0; m < 2; ++m) {
            int o = (m * 16 + ar) * PST + ks * 32 + kc;
            pah[m] = *(const short8*)(myPh + o);
            pal[m] = *(const short8*)(myPl + o);
        }
        #pragma unroll
        for (int n = 0; n < 4; ++n) {
            size_t o = ((size_t)b * 512 + head * 64 + n * 16 + ar) * 96 + ks * 32 + kc;
            short8 bh = *(const short8*)(vTh + o);
            short8 bl = *(const short8*)(vTl + o);
            #pragma unroll
            for (int m = 0; m < 2; ++m) {
                accp[m][n] = mfma16(pah[m], bh, accp[m][n]);
                accp[m][n] = mfma16(pah[m], bl, accp[m][n]);
                accp[m][n] = mfma16(pal[m], bh, accp[m][n]);
            }
        }
    }

    #pragma unroll
    for (int m = 0; m < 2; ++m) {
        #pragma unroll
        for (int n = 0; n < 4; ++n) {
            #pragma unroll
            for (int r = 0; r < 4; ++r) {
                size_t row = qrow0 + m * 16 + kg * 4 + r;
                int col = head * 64 + n * 16 + ar;
                float v = accp[m][n][r];
                u16 h = f2bf(v);
                outH[row * 512 + col] = h;
                outL[row * 512 + col] = f2bf(v - bf2f(h));
            }
        }
    }
}

extern "C" void kernel_launch(void* const* d_in, const int* in_sizes, int n_in,
                              void* d_out, int out_size, void* d_ws, size_t ws_size,
                              hipStream_t stream)
{
    const float* x    = (const float*)d_in[0];   // [16,4096,512]
    const float* ctx  = (const float*)d_in[1];   // [16,77,768]
    const float* Wq   = (const float*)d_in[2];   // [512,512]
    const float* Wk   = (const float*)d_in[3];   // [768,512]
    const float* Wv   = (const float*)d_in[4];   // [768,512]
    const float* Wout = (const float*)d_in[5];   // [512,512]
    const float* bout = (const float*)d_in[6];   // [512]

    char* ws = (char*)d_ws;
    size_t off = 0;
    auto alloc = [&](size_t bytes) -> void* {
        void* p = ws + off;
        off += (bytes + 255) & ~(size_t)255;
        return p;
    };
    u16* WqH = (u16*)alloc(512 * 512 * 2);
    u16* WqL = (u16*)alloc(512 * 512 * 2);
    u16* WkH = (u16*)alloc(768 * 512 * 2);
    u16* WkL = (u16*)alloc(768 * 512 * 2);
    u16* WvH = (u16*)alloc(768 * 512 * 2);
    u16* WvL = (u16*)alloc(768 * 512 * 2);
    u16* WoH = (u16*)alloc(512 * 512 * 2);
    u16* WoL = (u16*)alloc(512 * 512 * 2);
    u16* kH  = (u16*)alloc((size_t)1240 * 512 * 2);
    u16* kL  = (u16*)alloc((size_t)1240 * 512 * 2);
    u16* vTh = (u16*)alloc((size_t)16 * 512 * 96 * 2);
    u16* vTl = (u16*)alloc((size_t)16 * 512 * 96 * 2);
    // 128 MiB block: first holds x pair, later reused for attn pair (x dead by then)
    u16* xH = (u16*)alloc((size_t)65536 * 512 * 2);
    u16* xL = (u16*)alloc((size_t)65536 * 512 * 2);
    u16* attnH = xH;
    u16* attnL = xL;
    (void)ws_size; (void)in_sizes; (void)n_in; (void)out_size;

    // q pair lives in d_out (exactly 128 MiB), dead before final GEMM writes there
    u16* qH = (u16*)d_out;
    u16* qL = qH + (size_t)65536 * 512;

    hipMemsetAsync(vTh, 0, (size_t)16 * 512 * 96 * 2, stream);
    hipMemsetAsync(vTl, 0, (size_t)16 * 512 * 96 * 2, stream);
    hipMemsetAsync(kH + (size_t)1232 * 512, 0, (size_t)8 * 512 * 2, stream);
    hipMemsetAsync(kL + (size_t)1232 * 512, 0, (size_t)8 * 512 * 2, stream);

    // 0. split x -> pair
    split_x<<<dim3(2048), dim3(256), 0, stream>>>(x, xH, xL, 65536 * 512 / 4);

    // 1. weight splits (transposed)
    transpose_split<<<dim3(1024), dim3(256), 0, stream>>>(Wq, WqH, WqL, 512, 512);
    transpose_split<<<dim3(1536), dim3(256), 0, stream>>>(Wk, WkH, WkL, 768, 512);
    transpose_split<<<dim3(1536), dim3(256), 0, stream>>>(Wv, WvH, WvL, 768, 512);
    transpose_split<<<dim3(1024), dim3(256), 0, stream>>>(Wout, WoH, WoL, 512, 512);

    // 2. k/v projections (small, reg-staged)
    gemm_split<false, OUT_PAIR><<<dim3(10, 4), dim3(256), 0, stream>>>(
        ctx, WkH, WkL, (const float*)nullptr,
        (float*)nullptr, kH, kL, 1232, 512, 768);
    gemm_split<false, OUT_PAIRT><<<dim3(10, 4), dim3(256), 0, stream>>>(
        ctx, WvH, WvL, (const float*)nullptr,
        (float*)nullptr, vTh, vTl, 1232, 512, 768);

    // 3. q projection: xpair @ Wq -> q pair in d_out  (grid: N fastest)
    gemm_pair<false, OUT_PAIR><<<dim3(4, 512), dim3(256), 0, stream>>>(
        xH, xL, WqH, WqL, (const float*)nullptr,
        (float*)nullptr, qH, qL, 65536, 512, 512);

    // 4. attention -> attn pair (reuses xpair buffer)
    attn_mfma<<<dim3(32, 8, 16), dim3(256), 0, stream>>>(
        qH, qL, kH, kL, vTh, vTl, attnH, attnL);

    // 5. output projection + bias -> d_out  (grid: N fastest)
    gemm_pair<true, OUT_F32><<<dim3(4, 512), dim3(256), 0, stream>>>(
        attnH, attnL, WoH, WoL, bout,
        (float*)d_out, (u16*)nullptr, (u16*)nullptr, 65536, 512, 512);
}

// Round 5
// 321.449 us; speedup vs baseline: 2.7500x; 1.7579x over previous
//
#include <hip/hip_runtime.h>

// CrossAttention: B=16, Sq=4096, Dm=512, Skv=77, Dc=768, H=8, Dh=64, inner=512
// Single-pass fp16 MFMA pipeline (fp16 = 11 mantissa bits; per-GEMM rel err
// ~2^-11, chain stays ~5x under the 2.45e-2 absmax threshold):
//   0. cvt_h16  : x fp32 -> fp16                                   (ws, reused)
//   1. transpose_h16: W* fp32 [K][N] -> fp16 [N][K]                (ws)
//   2. gemm_ctx OUT_H : k = ctx@Wk -> fp16 [1240pad][512]          (ws)
//      gemm_ctx OUT_HT: v = ctx@Wv -> Vt fp16 [16][512][96pad]     (ws)
//   3. gemm_h16 OUT_H : q = xh@Wq -> fp16 [65536][512]             (d_out)
//   4. attn_h16: MFMA scores + in-reg fp32 softmax + MFMA PV       (ws, overwrites xh)
//   5. gemm_h16 OUT_F32+bias: out = attn@Wout + bout -> fp32       (d_out)
// Big GEMMs: dbuf LDS + issue-early global_load_lds (m97 recipe) + XCD swizzle.

typedef unsigned short u16;
typedef unsigned int u32;
typedef _Float16 f16;
typedef __attribute__((ext_vector_type(8))) _Float16 half8;
typedef __attribute__((ext_vector_type(4))) _Float16 half4;
typedef __attribute__((ext_vector_type(4))) float f32x4;

__device__ __forceinline__ f32x4 mfma16h(half8 a, half8 b, f32x4 c) {
    return __builtin_amdgcn_mfma_f32_16x16x32_f16(a, b, c, 0, 0, 0);
}
// async global->LDS, 16B per lane; LDS dest = wave-uniform base + lane*16
__device__ __forceinline__ void gl_lds16(const f16* g, f16* l) {
    __builtin_amdgcn_global_load_lds(
        (const __attribute__((address_space(1))) void*)g,
        (__attribute__((address_space(3))) void*)l, 16, 0, 0);
}

// ---------------- x -> fp16 (elementwise) ----------------
__global__ __launch_bounds__(256) void cvt_h16(
    const float* __restrict__ x, f16* __restrict__ xh, long n8)
{
    long i = blockIdx.x * 256 + threadIdx.x;
    const long stride = (long)gridDim.x * 256;
    for (; i < n8; i += stride) {
        float4 a = ((const float4*)x)[2 * i];
        float4 b = ((const float4*)x)[2 * i + 1];
        half8 h = { (f16)a.x, (f16)a.y, (f16)a.z, (f16)a.w,
                    (f16)b.x, (f16)b.y, (f16)b.z, (f16)b.w };
        ((half8*)xh)[i] = h;
    }
}

// ---------------- weight transpose -> fp16 ----------------
__global__ __launch_bounds__(256) void transpose_h16(
    const float* __restrict__ W, f16* __restrict__ Ht, int K, int N)
{
    int idx = blockIdx.x * 256 + threadIdx.x;
    if (idx >= N * K) return;
    int n = idx / K, k = idx - n * K;
    Ht[idx] = (f16)W[(size_t)k * N + n];
}

#define OUT_F32 0
#define OUT_H   1
#define OUT_HT  2   // v: row->(b=row/77, si), store [(b*512+col)*96 + si]

// ---------------- big fp16 GEMM: gl_lds dbuf staging ----------------
// A fp16 [M][K], B fp16 [N][K]; M,N multiples of 128, K multiple of 32.
// launch grid: dim3(N/128, M/128)  (N fastest for A-sharing locality)
template<bool BIAS, int OUTM>
__global__ __launch_bounds__(256) void gemm_h16(
    const f16* __restrict__ A, const f16* __restrict__ B,
    const float* __restrict__ bias, float* __restrict__ C,
    f16* __restrict__ CHalf, int M, int N, int K)
{
    __shared__ f16 sm[2][2][128 * 32];   // [buf][A,B]  32 KB total

    const int t = threadIdx.x;
    const int lane = t & 63;
    const int w = t >> 6;
    const int wr = w >> 1, wc = w & 1;           // 2x2 waves of 64x64

    // XCD-chunked bijective swizzle (nblk % 8 == 0 here: 2048)
    const int f = blockIdx.x + gridDim.x * blockIdx.y;
    const int cpx = (gridDim.x * gridDim.y) >> 3;
    const int logical = (f & 7) * cpx + (f >> 3);
    const int m0 = (logical / gridDim.x) * 128;
    const int n0 = (logical % gridDim.x) * 128;

    const int ar = lane & 15;
    const int kc = (lane >> 4) << 3;
    const int srow = lane >> 2;                  // staging row within 16-row chunk
    const int scol = (lane & 3) << 3;            // staging f16 col 0/8/16/24

    f32x4 acc[4][4] = {};

    auto STAGE = [&](int buf, int k0) {
        #pragma unroll
        for (int j = 0; j < 2; ++j) {
            const int ci = w * 2 + j;            // chunk 0..7 -> rows ci*16..+15
            const int r = ci * 16 + srow;
            gl_lds16(A + (size_t)(m0 + r) * K + k0 + scol, &sm[buf][0][ci * 512]);
            gl_lds16(B + (size_t)(n0 + r) * K + k0 + scol, &sm[buf][1][ci * 512]);
        }
    };

    const int nk = K >> 5;
    STAGE(0, 0);
    __syncthreads();

    int cur = 0;
    for (int kt = 0; kt < nk; ++kt) {
        if (kt + 1 < nk) STAGE(cur ^ 1, (kt + 1) << 5);

        const f16* pA = sm[cur][0];
        const f16* pB = sm[cur][1];

        half8 fa[4], fb[4];
        #pragma unroll
        for (int m = 0; m < 4; ++m)
            fa[m] = *(const half8*)(pA + (wr * 64 + m * 16 + ar) * 32 + kc);
        #pragma unroll
        for (int n = 0; n < 4; ++n)
            fb[n] = *(const half8*)(pB + (wc * 64 + n * 16 + ar) * 32 + kc);

        __builtin_amdgcn_s_setprio(1);
        #pragma unroll
        for (int m = 0; m < 4; ++m)
            #pragma unroll
            for (int n = 0; n < 4; ++n)
                acc[m][n] = mfma16h(fa[m], fb[n], acc[m][n]);
        __builtin_amdgcn_s_setprio(0);
        __syncthreads();
        cur ^= 1;
    }

    #pragma unroll
    for (int n = 0; n < 4; ++n) {
        int col = n0 + wc * 64 + n * 16 + ar;
        float bv = 0.f;
        if constexpr (BIAS) bv = bias[col];
        #pragma unroll
        for (int m = 0; m < 4; ++m) {
            #pragma unroll
            for (int r = 0; r < 4; ++r) {
                int row = m0 + wr * 64 + m * 16 + ((lane >> 4) << 2) + r;
                float v = acc[m][n][r] + bv;
                if constexpr (OUTM == OUT_F32) {
                    C[(size_t)row * N + col] = v;
                } else {
                    CHalf[(size_t)row * N + col] = (f16)v;
                }
            }
        }
    }
}

// ---------------- ctx GEMM (kv projections, reg-staged fp32->fp16) ----------
#define PK 40   // padded LDS K-stride

template<int OUTM>
__global__ __launch_bounds__(256) void gemm_ctx(
    const float* __restrict__ A, const f16* __restrict__ Bt,
    f16* __restrict__ CH, int M, int N, int K)
{
    __shared__ f16 lA[128 * PK];
    __shared__ f16 lB[128 * PK];

    const int t = threadIdx.x;
    const int lane = t & 63;
    const int wid = t >> 6;
    const int wr = wid >> 1, wc = wid & 1;
    const int m0 = blockIdx.x * 128, n0 = blockIdx.y * 128;
    const int ar = lane & 15;
    const int kc = (lane >> 4) << 3;

    f32x4 acc[4][4] = {};

    for (int k0 = 0; k0 < K; k0 += 32) {
        #pragma unroll
        for (int it = 0; it < 4; ++it) {
            int idx = t + it * 256;
            int row = idx >> 3;
            int c4 = (idx & 7) << 2;
            int gr = m0 + row;
            float4 v = make_float4(0.f, 0.f, 0.f, 0.f);
            if (gr < M) v = *(const float4*)(A + (size_t)gr * K + k0 + c4);
            *(half4*)(lA + row * PK + c4) = (half4){(f16)v.x, (f16)v.y, (f16)v.z, (f16)v.w};
        }
        #pragma unroll
        for (int it = 0; it < 2; ++it) {
            int idx = t + it * 256;
            int row = idx >> 2;
            int c8 = (idx & 3) << 3;
            *(half8*)(lB + row * PK + c8) =
                *(const half8*)(Bt + (size_t)(n0 + row) * K + k0 + c8);
        }
        __syncthreads();

        half8 fa[4], fb[4];
        #pragma unroll
        for (int m = 0; m < 4; ++m)
            fa[m] = *(const half8*)(lA + (wr * 64 + m * 16 + ar) * PK + kc);
        #pragma unroll
        for (int n = 0; n < 4; ++n)
            fb[n] = *(const half8*)(lB + (wc * 64 + n * 16 + ar) * PK + kc);
        #pragma unroll
        for (int m = 0; m < 4; ++m)
            #pragma unroll
            for (int n = 0; n < 4; ++n)
                acc[m][n] = mfma16h(fa[m], fb[n], acc[m][n]);
        __syncthreads();
    }

    #pragma unroll
    for (int n = 0; n < 4; ++n) {
        int col = n0 + wc * 64 + n * 16 + ar;
        #pragma unroll
        for (int m = 0; m < 4; ++m) {
            #pragma unroll
            for (int r = 0; r < 4; ++r) {
                int row = m0 + wr * 64 + m * 16 + ((lane >> 4) << 2) + r;
                if (row < M) {
                    float v = acc[m][n][r];
                    if constexpr (OUTM == OUT_H) {
                        CH[(size_t)row * N + col] = (f16)v;
                    } else {
                        int bb = row / 77;
                        int si = row - bb * 77;
                        CH[((size_t)bb * 512 + col) * 96 + si] = (f16)v;
                    }
                }
            }
        }
    }
}

// ---------------- MFMA attention (fp16 inputs, fp32 softmax) ----------------
// grid (Sq/128, H, B), block 256 (4 waves, 32 q-rows each).
__global__ __launch_bounds__(256) void attn_h16(
    const f16* __restrict__ q, const f16* __restrict__ k,
    const f16* __restrict__ vT, f16* __restrict__ outA)
{
    constexpr int PST = 104;   // P LDS stride (f16): rows 16B-aligned
    __shared__ f16 sP[4 * 32 * PST];

    const int t = threadIdx.x;
    const int lane = t & 63;
    const int w = t >> 6;
    const int ar = lane & 15;
    const int kg = lane >> 4;
    const int kc = kg << 3;
    const int b = blockIdx.z, head = blockIdx.y;
    const size_t qrow0 = (size_t)b * 4096 + blockIdx.x * 128 + w * 32;

    // ---- scores [32 q][80 si], K-dim = 64 ----
    f32x4 accs[2][5] = {};
    #pragma unroll
    for (int ks = 0; ks < 2; ++ks) {
        const int d = head * 64 + ks * 32 + kc;
        half8 ah[2];
        #pragma unroll
        for (int m = 0; m < 2; ++m)
            ah[m] = *(const half8*)(q + (qrow0 + m * 16 + ar) * 512 + d);
        #pragma unroll
        for (int n = 0; n < 5; ++n) {
            half8 bh = *(const half8*)(k + ((size_t)(b * 77 + n * 16 + ar)) * 512 + d);
            #pragma unroll
            for (int m = 0; m < 2; ++m)
                accs[m][n] = mfma16h(ah[m], bh, accs[m][n]);
        }
    }

    // ---- softmax in registers (rows on 16-lane groups) ----
    #pragma unroll
    for (int m = 0; m < 2; ++m) {
        #pragma unroll
        for (int r = 0; r < 4; ++r) {
            float mx = -1e30f;
            #pragma unroll
            for (int n = 0; n < 5; ++n) {
                float v = accs[m][n][r] * 0.125f;          // * D_HEAD^-0.5
                if (n == 4 && ar >= 13) v = -1e30f;        // mask si >= 77
                accs[m][n][r] = v;
                mx = fmaxf(mx, v);
            }
            mx = fmaxf(mx, __shfl_xor(mx, 1));
            mx = fmaxf(mx, __shfl_xor(mx, 2));
            mx = fmaxf(mx, __shfl_xor(mx, 4));
            mx = fmaxf(mx, __shfl_xor(mx, 8));
            float sum = 0.f;
            #pragma unroll
            for (int n = 0; n < 5; ++n) {
                float e = __expf(accs[m][n][r] - mx);
                accs[m][n][r] = e;
                sum += e;
            }
            sum += __shfl_xor(sum, 1);
            sum += __shfl_xor(sum, 2);
            sum += __shfl_xor(sum, 4);
            sum += __shfl_xor(sum, 8);
            float inv = 1.f / sum;
            #pragma unroll
            for (int n = 0; n < 5; ++n) accs[m][n][r] *= inv;
        }
    }

    // ---- P -> LDS fp16, zero-pad cols 80..103 ----
    f16* myP = sP + w * 32 * PST;
    for (int i = lane; i < 32 * 12; i += 64) {
        int row = i / 12, c = 80 + (i % 12) * 2;
        *(u32*)(myP + row * PST + c) = 0;
    }
    #pragma unroll
    for (int m = 0; m < 2; ++m)
        #pragma unroll
        for (int n = 0; n < 5; ++n)
            #pragma unroll
            for (int r = 0; r < 4; ++r)
                myP[(m * 16 + kg * 4 + r) * PST + n * 16 + ar] = (f16)accs[m][n][r];
    __syncthreads();

    // ---- PV [32 q][64 d], K-dim = 96 (zero-padded) ----
    f32x4 accp[2][4] = {};
    #pragma unroll
    for (int ks = 0; ks < 3; ++ks) {
        half8 pa[2];
        #pragma unroll
        for (int m = 0; m < 2; ++m)
            pa[m] = *(const half8*)(myP + (m * 16 + ar) * PST + ks * 32 + kc);
        #pragma unroll
        for (int n = 0; n < 4; ++n) {
            half8 bh = *(const half8*)(vT + ((size_t)b * 512 + head * 64 + n * 16 + ar) * 96 + ks * 32 + kc);
            #pragma unroll
            for (int m = 0; m < 2; ++m)
                accp[m][n] = mfma16h(pa[m], bh, accp[m][n]);
        }
    }

    // ---- store attn output fp16 ----
    #pragma unroll
    for (int m = 0; m < 2; ++m)
        #pragma unroll
        for (int n = 0; n < 4; ++n)
            #pragma unroll
            for (int r = 0; r < 4; ++r)
                outA[(qrow0 + m * 16 + kg * 4 + r) * 512 + head * 64 + n * 16 + ar]
                    = (f16)accp[m][n][r];
}

extern "C" void kernel_launch(void* const* d_in, const int* in_sizes, int n_in,
                              void* d_out, int out_size, void* d_ws, size_t ws_size,
                              hipStream_t stream)
{
    const float* x    = (const float*)d_in[0];   // [16,4096,512]
    const float* ctx  = (const float*)d_in[1];   // [16,77,768]
    const float* Wq   = (const float*)d_in[2];   // [512,512]
    const float* Wk   = (const float*)d_in[3];   // [768,512]
    const float* Wv   = (const float*)d_in[4];   // [768,512]
    const float* Wout = (const float*)d_in[5];   // [512,512]
    const float* bout = (const float*)d_in[6];   // [512]

    char* ws = (char*)d_ws;
    size_t off = 0;
    auto alloc = [&](size_t bytes) -> void* {
        void* p = ws + off;
        off += (bytes + 255) & ~(size_t)255;
        return p;
    };
    f16* WqT = (f16*)alloc(512 * 512 * 2);
    f16* WkT = (f16*)alloc(768 * 512 * 2);
    f16* WvT = (f16*)alloc(768 * 512 * 2);
    f16* WoT = (f16*)alloc(512 * 512 * 2);
    f16* kbuf = (f16*)alloc((size_t)1240 * 512 * 2);     // 1232 rows + zero pad
    f16* vT   = (f16*)alloc((size_t)16 * 512 * 96 * 2);  // [b][col][si pad 96]
    // 64 MiB block: first holds x fp16, later reused for attn out (x dead by then)
    f16* xh = (f16*)alloc((size_t)65536 * 512 * 2);
    f16* attnA = xh;
    (void)ws_size; (void)in_sizes; (void)n_in; (void)out_size;

    // q fp16 lives in d_out (67 MB of 128 MB), dead before final GEMM writes
    f16* qh = (f16*)d_out;

    hipMemsetAsync(vT, 0, (size_t)16 * 512 * 96 * 2, stream);
    hipMemsetAsync(kbuf + (size_t)1232 * 512, 0, (size_t)8 * 512 * 2, stream);

    // 0. x -> fp16
    cvt_h16<<<dim3(2048), dim3(256), 0, stream>>>(x, xh, (long)65536 * 512 / 8);

    // 1. weight transposes -> fp16
    transpose_h16<<<dim3(1024), dim3(256), 0, stream>>>(Wq, WqT, 512, 512);
    transpose_h16<<<dim3(1536), dim3(256), 0, stream>>>(Wk, WkT, 768, 512);
    transpose_h16<<<dim3(1536), dim3(256), 0, stream>>>(Wv, WvT, 768, 512);
    transpose_h16<<<dim3(1024), dim3(256), 0, stream>>>(Wout, WoT, 512, 512);

    // 2. k/v projections
    gemm_ctx<OUT_H><<<dim3(10, 4), dim3(256), 0, stream>>>(
        ctx, WkT, kbuf, 1232, 512, 768);
    gemm_ctx<OUT_HT><<<dim3(10, 4), dim3(256), 0, stream>>>(
        ctx, WvT, vT, 1232, 512, 768);

    // 3. q projection: xh @ Wq -> q fp16 in d_out  (grid: N fastest)
    gemm_h16<false, OUT_H><<<dim3(4, 512), dim3(256), 0, stream>>>(
        xh, WqT, (const float*)nullptr, (float*)nullptr, qh, 65536, 512, 512);

    // 4. attention -> attn fp16 (reuses xh buffer)
    attn_h16<<<dim3(32, 8, 16), dim3(256), 0, stream>>>(qh, kbuf, vT, attnA);

    // 5. output projection + bias -> d_out fp32  (grid: N fastest)
    gemm_h16<true, OUT_F32><<<dim3(4, 512), dim3(256), 0, stream>>>(
        attnA, WoT, bout, (float*)d_out, (f16*)nullptr, 65536, 512, 512);
}

// Round 6
// 319.520 us; speedup vs baseline: 2.7666x; 1.0060x over previous
//
#include <hip/hip_runtime.h>

// CrossAttention: B=16, Sq=4096, Dm=512, Skv=77, Dc=768, H=8, Dh=64, inner=512
// Single-pass fp16 MFMA pipeline (fp16 = 11 mantissa bits; per-GEMM rel err
// ~2^-11, chain stays ~3x under the 2.45e-2 absmax threshold):
//   0. pad_fill : zero vT si-pad + kbuf row-pad (replaces pathological
//                 graph-captured hipMemsetAsync nodes, ~90us/replay)
//   1. cvt_h16  : x fp32 -> fp16                                   (ws, reused)
//   2. transpose_h16: W* fp32 [K][N] -> fp16 [N][K]                (ws)
//   3. gemm_ctx OUT_H : k = ctx@Wk -> fp16 [1240pad][512]          (ws)
//      gemm_ctx OUT_HT: v = ctx@Wv -> Vt fp16 [16][512][96pad]     (ws)
//   4. gemm_h16 OUT_H : q = xh@Wq -> fp16 [65536][512]             (d_out)
//   5. attn_h16: MFMA scores + in-reg fp32 softmax + MFMA PV       (ws, overwrites xh)
//   6. gemm_h16 OUT_F32+bias: out = attn@Wout + bout -> fp32       (d_out)
// Big GEMMs: dbuf LDS + issue-early global_load_lds (m97 recipe) + XCD swizzle.

typedef unsigned short u16;
typedef unsigned int u32;
typedef _Float16 f16;
typedef __attribute__((ext_vector_type(8))) _Float16 half8;
typedef __attribute__((ext_vector_type(4))) _Float16 half4;
typedef __attribute__((ext_vector_type(4))) float f32x4;

__device__ __forceinline__ f32x4 mfma16h(half8 a, half8 b, f32x4 c) {
    return __builtin_amdgcn_mfma_f32_16x16x32_f16(a, b, c, 0, 0, 0);
}
// async global->LDS, 16B per lane; LDS dest = wave-uniform base + lane*16
__device__ __forceinline__ void gl_lds16(const f16* g, f16* l) {
    __builtin_amdgcn_global_load_lds(
        (const __attribute__((address_space(1))) void*)g,
        (__attribute__((address_space(3))) void*)l, 16, 0, 0);
}

// ---------------- pad fill (replaces hipMemsetAsync graph nodes) ----------
// vT pad: si in [77,96) for each of 16*512 (b,col) groups; kbuf rows 1232..1239
__global__ __launch_bounds__(256) void pad_fill(
    f16* __restrict__ vT, f16* __restrict__ kbuf)
{
    const int nv = 16 * 512 * 19;
    int i = blockIdx.x * 256 + threadIdx.x;
    if (i < nv) {
        int g = i / 19, s = i - g * 19;
        vT[(size_t)g * 96 + 77 + s] = (f16)0.f;
    } else {
        int j = i - nv;
        if (j < 8 * 512) kbuf[(size_t)1232 * 512 + j] = (f16)0.f;
    }
}

// ---------------- x -> fp16 (elementwise) ----------------
__global__ __launch_bounds__(256) void cvt_h16(
    const float* __restrict__ x, f16* __restrict__ xh, long n8)
{
    long i = blockIdx.x * 256 + threadIdx.x;
    const long stride = (long)gridDim.x * 256;
    for (; i < n8; i += stride) {
        float4 a = ((const float4*)x)[2 * i];
        float4 b = ((const float4*)x)[2 * i + 1];
        half8 h = { (f16)a.x, (f16)a.y, (f16)a.z, (f16)a.w,
                    (f16)b.x, (f16)b.y, (f16)b.z, (f16)b.w };
        ((half8*)xh)[i] = h;
    }
}

// ---------------- weight transpose -> fp16 ----------------
__global__ __launch_bounds__(256) void transpose_h16(
    const float* __restrict__ W, f16* __restrict__ Ht, int K, int N)
{
    int idx = blockIdx.x * 256 + threadIdx.x;
    if (idx >= N * K) return;
    int n = idx / K, k = idx - n * K;
    Ht[idx] = (f16)W[(size_t)k * N + n];
}

#define OUT_F32 0
#define OUT_H   1
#define OUT_HT  2   // v: row->(b=row/77, si), store [(b*512+col)*96 + si]

// ---------------- big fp16 GEMM: gl_lds dbuf staging ----------------
// A fp16 [M][K], B fp16 [N][K]; M,N multiples of 128, K multiple of 32.
// launch grid: dim3(N/128, M/128)  (N fastest for A-sharing locality)
template<bool BIAS, int OUTM>
__global__ __launch_bounds__(256) void gemm_h16(
    const f16* __restrict__ A, const f16* __restrict__ B,
    const float* __restrict__ bias, float* __restrict__ C,
    f16* __restrict__ CHalf, int M, int N, int K)
{
    __shared__ f16 sm[2][2][128 * 32];   // [buf][A,B]  32 KB total

    const int t = threadIdx.x;
    const int lane = t & 63;
    const int w = t >> 6;
    const int wr = w >> 1, wc = w & 1;           // 2x2 waves of 64x64

    // XCD-chunked bijective swizzle (nblk % 8 == 0 here: 2048)
    const int f = blockIdx.x + gridDim.x * blockIdx.y;
    const int cpx = (gridDim.x * gridDim.y) >> 3;
    const int logical = (f & 7) * cpx + (f >> 3);
    const int m0 = (logical / gridDim.x) * 128;
    const int n0 = (logical % gridDim.x) * 128;

    const int ar = lane & 15;
    const int kc = (lane >> 4) << 3;
    const int srow = lane >> 2;                  // staging row within 16-row chunk
    const int scol = (lane & 3) << 3;            // staging f16 col 0/8/16/24

    f32x4 acc[4][4] = {};

    auto STAGE = [&](int buf, int k0) {
        #pragma unroll
        for (int j = 0; j < 2; ++j) {
            const int ci = w * 2 + j;            // chunk 0..7 -> rows ci*16..+15
            const int r = ci * 16 + srow;
            gl_lds16(A + (size_t)(m0 + r) * K + k0 + scol, &sm[buf][0][ci * 512]);
            gl_lds16(B + (size_t)(n0 + r) * K + k0 + scol, &sm[buf][1][ci * 512]);
        }
    };

    const int nk = K >> 5;
    STAGE(0, 0);
    __syncthreads();

    int cur = 0;
    for (int kt = 0; kt < nk; ++kt) {
        if (kt + 1 < nk) STAGE(cur ^ 1, (kt + 1) << 5);

        const f16* pA = sm[cur][0];
        const f16* pB = sm[cur][1];

        half8 fa[4], fb[4];
        #pragma unroll
        for (int m = 0; m < 4; ++m)
            fa[m] = *(const half8*)(pA + (wr * 64 + m * 16 + ar) * 32 + kc);
        #pragma unroll
        for (int n = 0; n < 4; ++n)
            fb[n] = *(const half8*)(pB + (wc * 64 + n * 16 + ar) * 32 + kc);

        __builtin_amdgcn_s_setprio(1);
        #pragma unroll
        for (int m = 0; m < 4; ++m)
            #pragma unroll
            for (int n = 0; n < 4; ++n)
                acc[m][n] = mfma16h(fa[m], fb[n], acc[m][n]);
        __builtin_amdgcn_s_setprio(0);
        __syncthreads();
        cur ^= 1;
    }

    #pragma unroll
    for (int n = 0; n < 4; ++n) {
        int col = n0 + wc * 64 + n * 16 + ar;
        float bv = 0.f;
        if constexpr (BIAS) bv = bias[col];
        #pragma unroll
        for (int m = 0; m < 4; ++m) {
            #pragma unroll
            for (int r = 0; r < 4; ++r) {
                int row = m0 + wr * 64 + m * 16 + ((lane >> 4) << 2) + r;
                float v = acc[m][n][r] + bv;
                if constexpr (OUTM == OUT_F32) {
                    C[(size_t)row * N + col] = v;
                } else {
                    CHalf[(size_t)row * N + col] = (f16)v;
                }
            }
        }
    }
}

// ---------------- ctx GEMM (kv projections, reg-staged fp32->fp16) ----------
#define PK 40   // padded LDS K-stride

template<int OUTM>
__global__ __launch_bounds__(256) void gemm_ctx(
    const float* __restrict__ A, const f16* __restrict__ Bt,
    f16* __restrict__ CH, int M, int N, int K)
{
    __shared__ f16 lA[128 * PK];
    __shared__ f16 lB[128 * PK];

    const int t = threadIdx.x;
    const int lane = t & 63;
    const int wid = t >> 6;
    const int wr = wid >> 1, wc = wid & 1;
    const int m0 = blockIdx.x * 128, n0 = blockIdx.y * 128;
    const int ar = lane & 15;
    const int kc = (lane >> 4) << 3;

    f32x4 acc[4][4] = {};

    for (int k0 = 0; k0 < K; k0 += 32) {
        #pragma unroll
        for (int it = 0; it < 4; ++it) {
            int idx = t + it * 256;
            int row = idx >> 3;
            int c4 = (idx & 7) << 2;
            int gr = m0 + row;
            float4 v = make_float4(0.f, 0.f, 0.f, 0.f);
            if (gr < M) v = *(const float4*)(A + (size_t)gr * K + k0 + c4);
            *(half4*)(lA + row * PK + c4) = (half4){(f16)v.x, (f16)v.y, (f16)v.z, (f16)v.w};
        }
        #pragma unroll
        for (int it = 0; it < 2; ++it) {
            int idx = t + it * 256;
            int row = idx >> 2;
            int c8 = (idx & 3) << 3;
            *(half8*)(lB + row * PK + c8) =
                *(const half8*)(Bt + (size_t)(n0 + row) * K + k0 + c8);
        }
        __syncthreads();

        half8 fa[4], fb[4];
        #pragma unroll
        for (int m = 0; m < 4; ++m)
            fa[m] = *(const half8*)(lA + (wr * 64 + m * 16 + ar) * PK + kc);
        #pragma unroll
        for (int n = 0; n < 4; ++n)
            fb[n] = *(const half8*)(lB + (wc * 64 + n * 16 + ar) * PK + kc);
        #pragma unroll
        for (int m = 0; m < 4; ++m)
            #pragma unroll
            for (int n = 0; n < 4; ++n)
                acc[m][n] = mfma16h(fa[m], fb[n], acc[m][n]);
        __syncthreads();
    }

    #pragma unroll
    for (int n = 0; n < 4; ++n) {
        int col = n0 + wc * 64 + n * 16 + ar;
        #pragma unroll
        for (int m = 0; m < 4; ++m) {
            #pragma unroll
            for (int r = 0; r < 4; ++r) {
                int row = m0 + wr * 64 + m * 16 + ((lane >> 4) << 2) + r;
                if (row < M) {
                    float v = acc[m][n][r];
                    if constexpr (OUTM == OUT_H) {
                        CH[(size_t)row * N + col] = (f16)v;
                    } else {
                        int bb = row / 77;
                        int si = row - bb * 77;
                        CH[((size_t)bb * 512 + col) * 96 + si] = (f16)v;
                    }
                }
            }
        }
    }
}

// ---------------- MFMA attention (fp16 inputs, fp32 softmax) ----------------
// grid (Sq/128, H, B), block 256 (4 waves, 32 q-rows each).
__global__ __launch_bounds__(256) void attn_h16(
    const f16* __restrict__ q, const f16* __restrict__ k,
    const f16* __restrict__ vT, f16* __restrict__ outA)
{
    constexpr int PST = 104;   // P LDS stride (f16): rows 16B-aligned
    __shared__ f16 sP[4 * 32 * PST];

    const int t = threadIdx.x;
    const int lane = t & 63;
    const int w = t >> 6;
    const int ar = lane & 15;
    const int kg = lane >> 4;
    const int kc = kg << 3;
    const int b = blockIdx.z, head = blockIdx.y;
    const size_t qrow0 = (size_t)b * 4096 + blockIdx.x * 128 + w * 32;

    // ---- scores [32 q][80 si], K-dim = 64 ----
    f32x4 accs[2][5] = {};
    #pragma unroll
    for (int ks = 0; ks < 2; ++ks) {
        const int d = head * 64 + ks * 32 + kc;
        half8 ah[2];
        #pragma unroll
        for (int m = 0; m < 2; ++m)
            ah[m] = *(const half8*)(q + (qrow0 + m * 16 + ar) * 512 + d);
        #pragma unroll
        for (int n = 0; n < 5; ++n) {
            half8 bh = *(const half8*)(k + ((size_t)(b * 77 + n * 16 + ar)) * 512 + d);
            #pragma unroll
            for (int m = 0; m < 2; ++m)
                accs[m][n] = mfma16h(ah[m], bh, accs[m][n]);
        }
    }

    // ---- softmax in registers (rows on 16-lane groups) ----
    #pragma unroll
    for (int m = 0; m < 2; ++m) {
        #pragma unroll
        for (int r = 0; r < 4; ++r) {
            float mx = -1e30f;
            #pragma unroll
            for (int n = 0; n < 5; ++n) {
                float v = accs[m][n][r] * 0.125f;          // * D_HEAD^-0.5
                if (n == 4 && ar >= 13) v = -1e30f;        // mask si >= 77 (kills NaN too)
                accs[m][n][r] = v;
                mx = fmaxf(mx, v);
            }
            mx = fmaxf(mx, __shfl_xor(mx, 1));
            mx = fmaxf(mx, __shfl_xor(mx, 2));
            mx = fmaxf(mx, __shfl_xor(mx, 4));
            mx = fmaxf(mx, __shfl_xor(mx, 8));
            float sum = 0.f;
            #pragma unroll
            for (int n = 0; n < 5; ++n) {
                float e = __expf(accs[m][n][r] - mx);
                accs[m][n][r] = e;
                sum += e;
            }
            sum += __shfl_xor(sum, 1);
            sum += __shfl_xor(sum, 2);
            sum += __shfl_xor(sum, 4);
            sum += __shfl_xor(sum, 8);
            float inv = 1.f / sum;
            #pragma unroll
            for (int n = 0; n < 5; ++n) accs[m][n][r] *= inv;
        }
    }

    // ---- P -> LDS fp16, zero-pad cols 80..103 ----
    f16* myP = sP + w * 32 * PST;
    for (int i = lane; i < 32 * 12; i += 64) {
        int row = i / 12, c = 80 + (i % 12) * 2;
        *(u32*)(myP + row * PST + c) = 0;
    }
    #pragma unroll
    for (int m = 0; m < 2; ++m)
        #pragma unroll
        for (int n = 0; n < 5; ++n)
            #pragma unroll
            for (int r = 0; r < 4; ++r)
                myP[(m * 16 + kg * 4 + r) * PST + n * 16 + ar] = (f16)accs[m][n][r];
    __syncthreads();

    // ---- PV [32 q][64 d], K-dim = 96 (zero-padded) ----
    f32x4 accp[2][4] = {};
    #pragma unroll
    for (int ks = 0; ks < 3; ++ks) {
        half8 pa[2];
        #pragma unroll
        for (int m = 0; m < 2; ++m)
            pa[m] = *(const half8*)(myP + (m * 16 + ar) * PST + ks * 32 + kc);
        #pragma unroll
        for (int n = 0; n < 4; ++n) {
            half8 bh = *(const half8*)(vT + ((size_t)b * 512 + head * 64 + n * 16 + ar) * 96 + ks * 32 + kc);
            #pragma unroll
            for (int m = 0; m < 2; ++m)
                accp[m][n] = mfma16h(pa[m], bh, accp[m][n]);
        }
    }

    // ---- store attn output fp16 ----
    #pragma unroll
    for (int m = 0; m < 2; ++m)
        #pragma unroll
        for (int n = 0; n < 4; ++n)
            #pragma unroll
            for (int r = 0; r < 4; ++r)
                outA[(qrow0 + m * 16 + kg * 4 + r) * 512 + head * 64 + n * 16 + ar]
                    = (f16)accp[m][n][r];
}

extern "C" void kernel_launch(void* const* d_in, const int* in_sizes, int n_in,
                              void* d_out, int out_size, void* d_ws, size_t ws_size,
                              hipStream_t stream)
{
    const float* x    = (const float*)d_in[0];   // [16,4096,512]
    const float* ctx  = (const float*)d_in[1];   // [16,77,768]
    const float* Wq   = (const float*)d_in[2];   // [512,512]
    const float* Wk   = (const float*)d_in[3];   // [768,512]
    const float* Wv   = (const float*)d_in[4];   // [768,512]
    const float* Wout = (const float*)d_in[5];   // [512,512]
    const float* bout = (const float*)d_in[6];   // [512]

    char* ws = (char*)d_ws;
    size_t off = 0;
    auto alloc = [&](size_t bytes) -> void* {
        void* p = ws + off;
        off += (bytes + 255) & ~(size_t)255;
        return p;
    };
    f16* WqT = (f16*)alloc(512 * 512 * 2);
    f16* WkT = (f16*)alloc(768 * 512 * 2);
    f16* WvT = (f16*)alloc(768 * 512 * 2);
    f16* WoT = (f16*)alloc(512 * 512 * 2);
    f16* kbuf = (f16*)alloc((size_t)1240 * 512 * 2);     // 1232 rows + zero pad
    f16* vT   = (f16*)alloc((size_t)16 * 512 * 96 * 2);  // [b][col][si pad 96]
    // 64 MiB block: first holds x fp16, later reused for attn out (x dead by then)
    f16* xh = (f16*)alloc((size_t)65536 * 512 * 2);
    f16* attnA = xh;
    (void)ws_size; (void)in_sizes; (void)n_in; (void)out_size;

    // q fp16 lives in d_out (67 MB of 128 MB), dead before final GEMM writes
    f16* qh = (f16*)d_out;

    // 0. zero pads (tiny kernel; graph-captured memset nodes cost ~90us/replay)
    pad_fill<<<dim3(625), dim3(256), 0, stream>>>(vT, kbuf);

    // 1. x -> fp16
    cvt_h16<<<dim3(2048), dim3(256), 0, stream>>>(x, xh, (long)65536 * 512 / 8);

    // 2. weight transposes -> fp16
    transpose_h16<<<dim3(1024), dim3(256), 0, stream>>>(Wq, WqT, 512, 512);
    transpose_h16<<<dim3(1536), dim3(256), 0, stream>>>(Wk, WkT, 768, 512);
    transpose_h16<<<dim3(1536), dim3(256), 0, stream>>>(Wv, WvT, 768, 512);
    transpose_h16<<<dim3(1024), dim3(256), 0, stream>>>(Wout, WoT, 512, 512);

    // 3. k/v projections
    gemm_ctx<OUT_H><<<dim3(10, 4), dim3(256), 0, stream>>>(
        ctx, WkT, kbuf, 1232, 512, 768);
    gemm_ctx<OUT_HT><<<dim3(10, 4), dim3(256), 0, stream>>>(
        ctx, WvT, vT, 1232, 512, 768);

    // 4. q projection: xh @ Wq -> q fp16 in d_out  (grid: N fastest)
    gemm_h16<false, OUT_H><<<dim3(4, 512), dim3(256), 0, stream>>>(
        xh, WqT, (const float*)nullptr, (float*)nullptr, qh, 65536, 512, 512);

    // 5. attention -> attn fp16 (reuses xh buffer)
    attn_h16<<<dim3(32, 8, 16), dim3(256), 0, stream>>>(qh, kbuf, vT, attnA);

    // 6. output projection + bias -> d_out fp32  (grid: N fastest)
    gemm_h16<true, OUT_F32><<<dim3(4, 512), dim3(256), 0, stream>>>(
        attnA, WoT, bout, (float*)d_out, (f16*)nullptr, 65536, 512, 512);
}